// Round 12
// baseline (147.647 us; speedup 1.0000x reference)
//
#include <hip/hip_runtime.h>

constexpr int Bn = 16;
constexpr int Tn = 512;
constexpr int Dn = 256;
constexpr int Vn = 4233;
constexpr int Vp = 4352;   // V padded to 34*128
constexpr int Ln = 64;     // LMAX
constexpr int Un = 80;     // glg2 row stride (65 used)
constexpr int CS = 68;     // ctc LDS row stride in floats
constexpr int NCB = 34;    // number of 128-wide vocab column blocks
constexpr int Mtot = Bn * Tn;  // 8192

#define LN2     0.6931471805599453f
#define INV_LN2 1.4426950408889634f

typedef __attribute__((ext_vector_type(8))) short short8;
typedef __attribute__((ext_vector_type(4))) float f32x4;

__device__ __forceinline__ float lg2(float x) { return __builtin_amdgcn_logf(x); }
__device__ __forceinline__ float ex2(float x) { return __builtin_amdgcn_exp2f(x); }

__device__ __forceinline__ unsigned short cvt_bf16(float f) {
    unsigned int u = __float_as_uint(f);
    u = (u + 0x7fffu + ((u >> 16) & 1u)) >> 16;
    return (unsigned short)u;
}

// async global->LDS, 16B per lane; LDS dest is wave-uniform base + lane*16
__device__ __forceinline__ void gl_lds16(const void* g, void* l) {
    __builtin_amdgcn_global_load_lds(
        (const __attribute__((address_space(1))) void*)g,
        (__attribute__((address_space(3))) void*)l,
        16, 0, 0);
}

// value from lane-1 (wave_shr:1); lane 0 takes `edge`
__device__ __forceinline__ float dpp_shr1_f(float v, float edge) {
    return __int_as_float(__builtin_amdgcn_update_dpp(
        __float_as_int(edge), __float_as_int(v), 0x138, 0xF, 0xF, false));
}
__device__ __forceinline__ int dpp_shr1_i(int v, int edge) {
    return __builtin_amdgcn_update_dpp(edge, v, 0x138, 0xF, 0xF, false);
}

// ---------------- conversion / gather prep ----------------
__global__ __launch_bounds__(256) void conv(
    const float* __restrict__ hs, const float* __restrict__ W,
    const float* __restrict__ bias, const int* __restrict__ ys,
    unsigned short* __restrict__ hs_b, unsigned short* __restrict__ w_b,
    unsigned short* __restrict__ wg_b, float* __restrict__ gbias)
{
    const int gid = blockIdx.x * 256 + threadIdx.x;
    const int stride = gridDim.x * 256;
    const float4* hs4 = (const float4*)hs;
    const float4* W4  = (const float4*)W;

    for (int i = gid; i < (Bn * Tn * Dn) / 4; i += stride) {
        float4 v = hs4[i];
        ushort4 o = make_ushort4(cvt_bf16(v.x), cvt_bf16(v.y), cvt_bf16(v.z), cvt_bf16(v.w));
        *(ushort4*)(&hs_b[i * 4]) = o;
    }
    for (int i = gid; i < Vp * (Dn / 4); i += stride) {
        int row = i >> 6;
        float4 v = make_float4(0.f, 0.f, 0.f, 0.f);
        if (row < Vn) v = W4[i];
        ushort4 o = make_ushort4(cvt_bf16(v.x), cvt_bf16(v.y), cvt_bf16(v.z), cvt_bf16(v.w));
        *(ushort4*)(&w_b[i * 4]) = o;
    }
    // gathered label rows, padded to 128 rows/batch (rows 65..127 zero)
    for (int i = gid; i < Bn * 128 * (Dn / 4); i += stride) {
        int b = i / (128 * (Dn / 4));
        int rem = i - b * (128 * (Dn / 4));
        int u = rem >> 6;
        int k4 = rem & 63;
        int v = (u == 0) ? 0 : ((u <= Ln) ? ys[b * Ln + u - 1] : -1);
        float4 val = make_float4(0.f, 0.f, 0.f, 0.f);
        if (v >= 0) val = W4[(size_t)v * (Dn / 4) + k4];
        ushort4 o = make_ushort4(cvt_bf16(val.x), cvt_bf16(val.y), cvt_bf16(val.z), cvt_bf16(val.w));
        *(ushort4*)(&wg_b[i * 4]) = o;
    }
    for (int i = gid; i < Bn * 128; i += stride) {
        int b = i >> 7;
        int u = i & 127;
        int v = (u == 0) ? 0 : ((u <= Ln) ? ys[b * Ln + u - 1] : -1);
        gbias[i] = (v >= 0) ? bias[v] : 0.0f;
    }
}

// ---------------- unified GEMM ----------------
// grid (64, 35). y<34: 128x128 vocab tile -> partial expsum sep[y][row].
// y==34: gathered-label tile (per-batch wg_b) -> raw log2-logits glg2.
// LDS XOR-swizzled (cg ^= row&7) to kill MFMA-read bank conflicts while
// keeping global_load_lds destinations contiguous.
__global__ __launch_bounds__(256) void gemm_se(
    const unsigned short* __restrict__ hs_b, const unsigned short* __restrict__ w_b,
    const unsigned short* __restrict__ wg_b, const float* __restrict__ bias,
    const float* __restrict__ gbias, float* __restrict__ sep,
    float* __restrict__ glg2)
{
    __shared__ __align__(16) short lsA[128 * 64];
    __shared__ __align__(16) short lsB[128 * 64];

    const int tid = threadIdx.x;
    const int lane = tid & 63;
    const int w = tid >> 6;
    const int lr = lane & 15;
    const int kq = lane >> 4;
    const int m0 = blockIdx.x * 128;
    const int mw = w * 32;
    const bool gather = (blockIdx.y == NCB);
    const int b = blockIdx.x >> 2;           // batch of this row tile

    const int srow = lane >> 3;
    const int scg  = (lane & 7) ^ (srow & 7);
    const int scol = scg * 8;

    const unsigned short* Bp = gather ? (wg_b + (size_t)b * 128 * Dn)
                                      : (w_b + (size_t)blockIdx.y * 128 * Dn);

    f32x4 acc[2][8];
    #pragma unroll
    for (int mf = 0; mf < 2; ++mf)
        #pragma unroll
        for (int nf = 0; nf < 8; ++nf)
            acc[mf][nf] = (f32x4){0.f, 0.f, 0.f, 0.f};

    for (int ks = 0; ks < 4; ++ks) {
        const int k0 = ks * 64;
        __syncthreads();
        #pragma unroll
        for (int j = 0; j < 4; ++j) {
            int c = w * 4 + j;
            int row = c * 8 + srow;
            gl_lds16(hs_b + (size_t)(m0 + row) * Dn + k0 + scol, (char*)lsA + c * 1024);
            gl_lds16(Bp   + (size_t)row * Dn + k0 + scol,        (char*)lsB + c * 1024);
        }
        __syncthreads();

        #pragma unroll
        for (int sub = 0; sub < 2; ++sub) {
            short8 af[2], bf[8];
            #pragma unroll
            for (int mf = 0; mf < 2; ++mf) {
                int row = mw + mf * 16 + lr;
                int cg = (sub * 4 + kq) ^ (row & 7);
                af[mf] = *(const short8*)(&lsA[row * 64 + cg * 8]);
            }
            #pragma unroll
            for (int nf = 0; nf < 8; ++nf) {
                int row = nf * 16 + lr;
                int cg = (sub * 4 + kq) ^ (row & 7);
                bf[nf] = *(const short8*)(&lsB[row * 64 + cg * 8]);
            }
            #pragma unroll
            for (int mf = 0; mf < 2; ++mf)
                #pragma unroll
                for (int nf = 0; nf < 8; ++nf)
                    acc[mf][nf] = __builtin_amdgcn_mfma_f32_16x16x32_bf16(
                        af[mf], bf[nf], acc[mf][nf], 0, 0, 0);
        }
    }

    if (!gather) {
        const int n0 = blockIdx.y * 128;
        float bcol[8]; bool valid[8];
        #pragma unroll
        for (int nf = 0; nf < 8; ++nf) {
            int col = n0 + nf * 16 + lr;
            valid[nf] = (col < Vn);
            bcol[nf] = valid[nf] ? bias[col] : 0.0f;
        }
        #pragma unroll
        for (int mf = 0; mf < 2; ++mf) {
            #pragma unroll
            for (int r = 0; r < 4; ++r) {
                float s = 0.0f;
                #pragma unroll
                for (int nf = 0; nf < 8; ++nf)
                    if (valid[nf]) s += __expf(acc[mf][nf][r] + bcol[nf]);
                #pragma unroll
                for (int off = 1; off < 16; off <<= 1) s += __shfl_xor(s, off, 64);
                if (lr == 0)
                    sep[(size_t)blockIdx.y * Mtot + m0 + mw + mf * 16 + kq * 4 + r] = s;
            }
        }
    } else {
        #pragma unroll
        for (int mf = 0; mf < 2; ++mf) {
            #pragma unroll
            for (int nf = 0; nf < 5; ++nf) {
                int u = nf * 16 + lr;
                float gv = gbias[b * 128 + u];
                #pragma unroll
                for (int r = 0; r < 4; ++r) {
                    int g = m0 + mw + mf * 16 + kq * 4 + r;
                    glg2[(size_t)g * Un + u] = (acc[mf][nf][r] + gv) * INV_LN2;
                }
            }
        }
    }
}

// ---------------- lse reduction: lse2[g] = log2(sum_c sep[c][g]) ----------------
__global__ __launch_bounds__(256) void lse_red(
    const float* __restrict__ sep, float* __restrict__ lse2)
{
    int g = blockIdx.x * 256 + threadIdx.x;
    float s = 0.0f;
    #pragma unroll
    for (int c = 0; c < NCB; ++c) s += sep[(size_t)c * Mtot + g];
    lse2[g] = lg2(s);
}

// ---------------- CTC forward recursion ----------------
// Linear domain, f32 mantissa + PER-LANE int exponent, renorm every step.
// State layout: lane l holds e = alpha[2l], o = alpha[2l+1]; z = alpha[128]
// (meaningful on lane 63 only, but updated lane-locally everywhere).
// Only alpha[2l-1] (o of lane l-1) crosses lanes: 1 float DPP + 1 int DPP.
// 4 waves stage 64-step chunks of p = exp2(glg2 - lse2) into double-buffered
// LDS; all waves run the recursion redundantly.
__global__ __launch_bounds__(256) void ctc_fwd(
    const float* __restrict__ glg2, const float* __restrict__ lse2,
    const int* __restrict__ ys, const int* __restrict__ hlens,
    const int* __restrict__ ylens, float* __restrict__ ll_out)
{
    __shared__ float ls[2][64 * CS + 4];
    __shared__ float shO[64], shE[64], shZ[64];
    __shared__ int   shX[64];

    const int b = blockIdx.x;
    const int tid = threadIdx.x;
    const int l = tid & 63;

    const int hl = hlens[b];
    int yl  = ys[b * Ln + l];
    int ylm = (l >= 1) ? ys[b * Ln + l - 1] : -1;
    const bool allow = (l >= 1) && (yl != ylm);   // s=2l+1 skip path

    const float* gb2 = glg2 + (size_t)b * Tn * Un;
    const float* lsb = lse2 + (size_t)b * Tn;

    // stage chunk 0: row tt <-> timestep t = 1 + tt
    #pragma unroll
    for (int j = 0; j < 4; ++j) {
        int i = tid + j * 256;
        int tt = i >> 4, u4 = (i & 15) * 4;
        float4 v = *(const float4*)(gb2 + (size_t)(1 + tt) * Un + u4);
        float sub = lsb[1 + tt];
        v.x = ex2(v.x - sub); v.y = ex2(v.y - sub);
        v.z = ex2(v.z - sub); v.w = ex2(v.w - sub);
        *(float4*)(&ls[0][tt * CS + u4]) = v;
    }
    if (tid < 64)
        ls[0][tid * CS + 64] = ex2(gb2[(size_t)(1 + tid) * Un + 64] - lsb[1 + tid]);
    __syncthreads();

    // t=0 init: alpha[0] = pb(0) (lane0 e), alpha[1] = p_y1(0) (lane0 o)
    float o = (l == 0) ? ex2(gb2[1] - lsb[0]) : 0.0f;
    float e = (l == 0) ? ex2(gb2[0] - lsb[0]) : 0.0f;
    float z = 0.0f;
    int ex = 0;

    float4 r4[4];
    float r1 = 0.0f;

#define STEP(PL, PB) do { \
        float oM1 = dpp_shr1_f(o, 0.0f); \
        int   xM1 = dpp_shr1_i(ex, -(1 << 28)); \
        int   et  = (ex > xM1) ? ex : xM1; \
        int   dwn = ex - et, dnn = xM1 - et; \
        float ao = ldexpf(o, dwn); \
        float ae = ldexpf(e, dwn); \
        float az = ldexpf(z, dwn); \
        float an = ldexpf(oM1, dnn); \
        float anA = allow ? an : 0.0f; \
        float uO = (ao + ae + anA) * (PL); \
        float uE = (ae + an) * (PB); \
        float uZ = (az + ao) * (PB); \
        float mm = fmaxf(fmaxf(uO, uE), uZ); \
        int dd = (int)((__float_as_uint(mm) >> 23) & 255u) - 127; \
        o = ldexpf(uO, -dd); \
        e = ldexpf(uE, -dd); \
        z = ldexpf(uZ, -dd); \
        ex = et + dd; \
    } while (0)

    for (int c = 0; c < 8; ++c) {
        if (c < 7) {
            const int tb = 1 + (c + 1) * 64;
            #pragma unroll
            for (int j = 0; j < 4; ++j) {
                int i = tid + j * 256;
                int tt = i >> 4, u4 = (i & 15) * 4;
                if (tb + tt < Tn) {
                    float4 v = *(const float4*)(gb2 + (size_t)(tb + tt) * Un + u4);
                    float sub = lsb[tb + tt];
                    v.x = ex2(v.x - sub); v.y = ex2(v.y - sub);
                    v.z = ex2(v.z - sub); v.w = ex2(v.w - sub);
                    r4[j] = v;
                } else {
                    r4[j] = make_float4(0.f, 0.f, 0.f, 0.f);
                }
            }
            if (tid < 64)
                r1 = (tb + tid < Tn)
                    ? ex2(gb2[(size_t)(tb + tid) * Un + 64] - lsb[tb + tid]) : 0.0f;
        }

        const float* buf = ls[c & 1];
        int lim = hl - 1 - c * 64;
        if (lim > 64) lim = 64;

        if (lim > 0) {
            float plC[8], pbC[8];
            #pragma unroll
            for (int j = 0; j < 8; ++j) {
                pbC[j] = buf[j * CS];
                plC[j] = buf[j * CS + 1 + l];
            }
            int tt = 0;
            for (; tt + 8 <= lim; tt += 8) {
                float plN[8], pbN[8];
                const bool more = (tt + 8 < 64);
                if (more) {
                    #pragma unroll
                    for (int j = 0; j < 8; ++j) {
                        pbN[j] = buf[(tt + 8 + j) * CS];
                        plN[j] = buf[(tt + 8 + j) * CS + 1 + l];
                    }
                }
                #pragma unroll
                for (int j = 0; j < 8; ++j) STEP(plC[j], pbC[j]);
                if (more) {
                    #pragma unroll
                    for (int j = 0; j < 8; ++j) { plC[j] = plN[j]; pbC[j] = pbN[j]; }
                }
            }
            for (int j = 0; tt < lim; ++tt, ++j) STEP(plC[j], pbC[j]);
        }

        if (c < 7) {
            float* dst = ls[(c + 1) & 1];
            #pragma unroll
            for (int j = 0; j < 4; ++j) {
                int i = tid + j * 256;
                int tt2 = i >> 4, u4 = (i & 15) * 4;
                *(float4*)(&dst[tt2 * CS + u4]) = r4[j];
            }
            if (tid < 64) dst[tid * CS + 64] = r1;
        }
        __syncthreads();
    }
#undef STEP

    if (tid < 64) { shO[l] = o; shE[l] = e; shZ[l] = z; shX[l] = ex; }
    __syncthreads();

    if (tid == 0) {
        int L = ylens[b];
        float vo = shO[L - 1]; int xo = shX[L - 1];     // alpha[2L-1]
        float ve; int xe;                                // alpha[2L]
        if (L == 64) { ve = shZ[63]; xe = shX[63]; }
        else         { ve = shE[L];  xe = shX[L]; }
        int em = (xo > xe) ? xo : xe;
        float s = ldexpf(vo, xo - em) + ldexpf(ve, xe - em);
        ll_out[b] = (lg2(s) + (float)em) * LN2;
    }
}

__global__ void finalize(const float* __restrict__ ll, float* __restrict__ out) {
    if (threadIdx.x == 0 && blockIdx.x == 0) {
        float s = 0.0f;
        #pragma unroll
        for (int b = 0; b < Bn; ++b) s += ll[b];
        out[0] = -s / (float)Bn;
    }
}

extern "C" void kernel_launch(void* const* d_in, const int* in_sizes, int n_in,
                              void* d_out, int out_size, void* d_ws, size_t ws_size,
                              hipStream_t stream) {
    const float* hs    = (const float*)d_in[0];
    const int*   hlens = (const int*)d_in[1];
    const int*   ys    = (const int*)d_in[2];
    const int*   ylens = (const int*)d_in[3];
    const float* W     = (const float*)d_in[4];
    const float* bias  = (const float*)d_in[5];
    float* out = (float*)d_out;

    char* ws = (char*)d_ws;
    unsigned short* hs_b = (unsigned short*)(ws);                       // 4,194,304 B
    unsigned short* w_b  = (unsigned short*)(ws + 4194304);             // 2,228,224 B
    unsigned short* wg_b = (unsigned short*)(ws + 6422528);             // 1,048,576 B
    float* glg2  = (float*)(ws + 7471104);                              // 2,621,440 B
    float* sep   = (float*)(ws + 10092544);                             // 1,114,112 B
    float* gbias = (float*)(ws + 11206656);                             //     8,192 B
    float* lse2  = (float*)(ws + 11214848);                             //    32,768 B
    float* ll    = (float*)(ws + 11247616);                             //        64 B

    conv<<<1024, 256, 0, stream>>>(hs, W, bias, ys, hs_b, w_b, wg_b, gbias);
    gemm_se<<<dim3(64, NCB + 1), 256, 0, stream>>>(hs_b, w_b, wg_b, bias, gbias, sep, glg2);
    lse_red<<<Mtot / 256, 256, 0, stream>>>(sep, lse2);
    ctc_fwd<<<Bn, 256, 0, stream>>>(glg2, lse2, ys, hlens, ylens, ll);
    finalize<<<1, 64, 0, stream>>>(ll, out);
}

// Round 14
// 143.053 us; speedup vs baseline: 1.0321x; 1.0321x over previous
//
#include <hip/hip_runtime.h>

constexpr int Bn = 16;
constexpr int Tn = 512;
constexpr int Dn = 256;
constexpr int Vn = 4233;
constexpr int Vp = 4352;   // V padded to 34*128
constexpr int Ln = 64;     // LMAX
constexpr int Un = 80;     // glg2/pmat row stride (65 used)
constexpr int CS = 68;     // ctc LDS row stride in floats
constexpr int NCB = 34;    // number of 128-wide vocab column blocks
constexpr int Mtot = Bn * Tn;  // 8192

#define LN2     0.6931471805599453f
#define INV_LN2 1.4426950408889634f

typedef __attribute__((ext_vector_type(8))) short short8;
typedef __attribute__((ext_vector_type(4))) float f32x4;

__device__ __forceinline__ float lg2(float x) { return __builtin_amdgcn_logf(x); }
__device__ __forceinline__ float ex2(float x) { return __builtin_amdgcn_exp2f(x); }

__device__ __forceinline__ unsigned short cvt_bf16(float f) {
    unsigned int u = __float_as_uint(f);
    u = (u + 0x7fffu + ((u >> 16) & 1u)) >> 16;
    return (unsigned short)u;
}

// async global->LDS, 16B per lane; LDS dest is wave-uniform base + lane*16
__device__ __forceinline__ void gl_lds16(const void* g, void* l) {
    __builtin_amdgcn_global_load_lds(
        (const __attribute__((address_space(1))) void*)g,
        (__attribute__((address_space(3))) void*)l,
        16, 0, 0);
}

// value from lane-1 (wave_shr:1); lane 0 takes `edge`
__device__ __forceinline__ float dpp_shr1_f(float v, float edge) {
    return __int_as_float(__builtin_amdgcn_update_dpp(
        __float_as_int(edge), __float_as_int(v), 0x138, 0xF, 0xF, false));
}
__device__ __forceinline__ int dpp_shr1_i(int v, int edge) {
    return __builtin_amdgcn_update_dpp(edge, v, 0x138, 0xF, 0xF, false);
}

// ---------------- conversion / gather prep ----------------
__global__ __launch_bounds__(256) void conv(
    const float* __restrict__ hs, const float* __restrict__ W,
    const float* __restrict__ bias, const int* __restrict__ ys,
    unsigned short* __restrict__ hs_b, unsigned short* __restrict__ w_b,
    unsigned short* __restrict__ wg_b, float* __restrict__ gbias)
{
    const int gid = blockIdx.x * 256 + threadIdx.x;
    const int stride = gridDim.x * 256;
    const float4* hs4 = (const float4*)hs;
    const float4* W4  = (const float4*)W;

    for (int i = gid; i < (Bn * Tn * Dn) / 4; i += stride) {
        float4 v = hs4[i];
        ushort4 o = make_ushort4(cvt_bf16(v.x), cvt_bf16(v.y), cvt_bf16(v.z), cvt_bf16(v.w));
        *(ushort4*)(&hs_b[i * 4]) = o;
    }
    for (int i = gid; i < Vp * (Dn / 4); i += stride) {
        int row = i >> 6;
        float4 v = make_float4(0.f, 0.f, 0.f, 0.f);
        if (row < Vn) v = W4[i];
        ushort4 o = make_ushort4(cvt_bf16(v.x), cvt_bf16(v.y), cvt_bf16(v.z), cvt_bf16(v.w));
        *(ushort4*)(&w_b[i * 4]) = o;
    }
    for (int i = gid; i < Bn * 128 * (Dn / 4); i += stride) {
        int b = i / (128 * (Dn / 4));
        int rem = i - b * (128 * (Dn / 4));
        int u = rem >> 6;
        int k4 = rem & 63;
        int v = (u == 0) ? 0 : ((u <= Ln) ? ys[b * Ln + u - 1] : -1);
        float4 val = make_float4(0.f, 0.f, 0.f, 0.f);
        if (v >= 0) val = W4[(size_t)v * (Dn / 4) + k4];
        ushort4 o = make_ushort4(cvt_bf16(val.x), cvt_bf16(val.y), cvt_bf16(val.z), cvt_bf16(val.w));
        *(ushort4*)(&wg_b[i * 4]) = o;
    }
    for (int i = gid; i < Bn * 128; i += stride) {
        int b = i >> 7;
        int u = i & 127;
        int v = (u == 0) ? 0 : ((u <= Ln) ? ys[b * Ln + u - 1] : -1);
        gbias[i] = (v >= 0) ? bias[v] : 0.0f;
    }
}

// ---------------- unified GEMM ----------------
// grid (64, 35). y<34: 128x128 vocab tile -> partial expsum sep[y][row].
// y==34: gathered-label tile (per-batch wg_b) -> raw log2-logits glg2.
// LDS XOR-swizzled (cg ^= row&7): MFMA reads conflict-free, staging contiguous.
__global__ __launch_bounds__(256) void gemm_se(
    const unsigned short* __restrict__ hs_b, const unsigned short* __restrict__ w_b,
    const unsigned short* __restrict__ wg_b, const float* __restrict__ bias,
    const float* __restrict__ gbias, float* __restrict__ sep,
    float* __restrict__ glg2)
{
    __shared__ __align__(16) short lsA[128 * 64];
    __shared__ __align__(16) short lsB[128 * 64];

    const int tid = threadIdx.x;
    const int lane = tid & 63;
    const int w = tid >> 6;
    const int lr = lane & 15;
    const int kq = lane >> 4;
    const int m0 = blockIdx.x * 128;
    const int mw = w * 32;
    const bool gather = (blockIdx.y == NCB);
    const int b = blockIdx.x >> 2;

    const int srow = lane >> 3;
    const int scg  = (lane & 7) ^ (srow & 7);
    const int scol = scg * 8;

    const unsigned short* Bp = gather ? (wg_b + (size_t)b * 128 * Dn)
                                      : (w_b + (size_t)blockIdx.y * 128 * Dn);

    f32x4 acc[2][8];
    #pragma unroll
    for (int mf = 0; mf < 2; ++mf)
        #pragma unroll
        for (int nf = 0; nf < 8; ++nf)
            acc[mf][nf] = (f32x4){0.f, 0.f, 0.f, 0.f};

    for (int ks = 0; ks < 4; ++ks) {
        const int k0 = ks * 64;
        __syncthreads();
        #pragma unroll
        for (int j = 0; j < 4; ++j) {
            int c = w * 4 + j;
            int row = c * 8 + srow;
            gl_lds16(hs_b + (size_t)(m0 + row) * Dn + k0 + scol, (char*)lsA + c * 1024);
            gl_lds16(Bp   + (size_t)row * Dn + k0 + scol,        (char*)lsB + c * 1024);
        }
        __syncthreads();

        #pragma unroll
        for (int sub = 0; sub < 2; ++sub) {
            short8 af[2], bf[8];
            #pragma unroll
            for (int mf = 0; mf < 2; ++mf) {
                int row = mw + mf * 16 + lr;
                int cg = (sub * 4 + kq) ^ (row & 7);
                af[mf] = *(const short8*)(&lsA[row * 64 + cg * 8]);
            }
            #pragma unroll
            for (int nf = 0; nf < 8; ++nf) {
                int row = nf * 16 + lr;
                int cg = (sub * 4 + kq) ^ (row & 7);
                bf[nf] = *(const short8*)(&lsB[row * 64 + cg * 8]);
            }
            #pragma unroll
            for (int mf = 0; mf < 2; ++mf)
                #pragma unroll
                for (int nf = 0; nf < 8; ++nf)
                    acc[mf][nf] = __builtin_amdgcn_mfma_f32_16x16x32_bf16(
                        af[mf], bf[nf], acc[mf][nf], 0, 0, 0);
        }
    }

    if (!gather) {
        const int n0 = blockIdx.y * 128;
        float bcol[8]; bool valid[8];
        #pragma unroll
        for (int nf = 0; nf < 8; ++nf) {
            int col = n0 + nf * 16 + lr;
            valid[nf] = (col < Vn);
            bcol[nf] = valid[nf] ? bias[col] : 0.0f;
        }
        #pragma unroll
        for (int mf = 0; mf < 2; ++mf) {
            #pragma unroll
            for (int r = 0; r < 4; ++r) {
                float s = 0.0f;
                #pragma unroll
                for (int nf = 0; nf < 8; ++nf)
                    if (valid[nf]) s += __expf(acc[mf][nf][r] + bcol[nf]);
                #pragma unroll
                for (int off = 1; off < 16; off <<= 1) s += __shfl_xor(s, off, 64);
                if (lr == 0)
                    sep[(size_t)blockIdx.y * Mtot + m0 + mw + mf * 16 + kq * 4 + r] = s;
            }
        }
    } else {
        #pragma unroll
        for (int mf = 0; mf < 2; ++mf) {
            #pragma unroll
            for (int nf = 0; nf < 5; ++nf) {
                int u = nf * 16 + lr;
                float gv = gbias[b * 128 + u];
                #pragma unroll
                for (int r = 0; r < 4; ++r) {
                    int g = m0 + mw + mf * 16 + kq * 4 + r;
                    glg2[(size_t)g * Un + u] = (acc[mf][nf][r] + gv) * INV_LN2;
                }
            }
        }
    }
}

// ---------------- lse + in-place normalize: glg2 <- exp2(glg2 - log2 sum) ----
// Block handles 64 rows; coalesced float4 transform. ctc_fwd then reads pure
// linear probs (no transcendentals on its serial path).
__global__ __launch_bounds__(256) void lse_norm(
    const float* __restrict__ sep, float* __restrict__ glg2)
{
    __shared__ float sl[64];
    const int tid = threadIdx.x;
    const int g0 = blockIdx.x * 64;

    if (tid < 64) {
        float s = 0.0f;
        #pragma unroll
        for (int c = 0; c < NCB; ++c) s += sep[(size_t)c * Mtot + g0 + tid];
        sl[tid] = lg2(s);
    }
    __syncthreads();

    #pragma unroll
    for (int j = 0; j < 4; ++j) {
        int i = tid + j * 256;           // 1024 = 64 rows x 16 float4
        int row = i >> 4, u4 = (i & 15) * 4;
        float* p = glg2 + (size_t)(g0 + row) * Un + u4;
        float4 v = *(const float4*)p;
        float sub = sl[row];
        v.x = ex2(v.x - sub); v.y = ex2(v.y - sub);
        v.z = ex2(v.z - sub); v.w = ex2(v.w - sub);
        *(float4*)p = v;
    }
    if (tid < 64) {
        float* p = glg2 + (size_t)(g0 + tid) * Un + 64;
        *p = ex2(*p - sl[tid]);
    }
}

// ---------------- CTC forward recursion ----------------
// Linear f32 mantissa + per-lane int exponent, renorm every step.
// Lane l: e=alpha[2l], o=alpha[2l+1]; z=alpha[128] (lane 63).
// ALL register arrays constant-indexed (round-12's dynamic tail indexing
// demoted them to scratch -> the 120cy/step stall). Tail via `act` predicate.
__global__ __launch_bounds__(256) void ctc_fwd(
    const float* __restrict__ pmat, const int* __restrict__ ys,
    const int* __restrict__ hlens, const int* __restrict__ ylens,
    float* __restrict__ ll_out)
{
    __shared__ float ls[2][64 * CS + 4];
    __shared__ float shO[64], shE[64], shZ[64];
    __shared__ int   shX[64];

    const int b = blockIdx.x;
    const int tid = threadIdx.x;
    const int l = tid & 63;

    const int hl = hlens[b];
    int yl  = ys[b * Ln + l];
    int ylm = (l >= 1) ? ys[b * Ln + l - 1] : -1;
    const float allowF = ((l >= 1) && (yl != ylm)) ? 1.0f : 0.0f;

    const float* pm = pmat + (size_t)b * Tn * Un;

    // stage chunk 0 (t = 1 + tt)
    #pragma unroll
    for (int j = 0; j < 4; ++j) {
        int i = tid + j * 256;
        int tt = i >> 4, u4 = (i & 15) * 4;
        *(float4*)(&ls[0][tt * CS + u4]) = *(const float4*)(pm + (size_t)(1 + tt) * Un + u4);
    }
    if (tid < 64) ls[0][tid * CS + 64] = pm[(size_t)(1 + tid) * Un + 64];
    __syncthreads();

    // t=0 init
    float o = (l == 0) ? pm[1] : 0.0f;
    float e = (l == 0) ? pm[0] : 0.0f;
    float z = 0.0f;
    int ex = 0;

    float4 r4a = make_float4(0.f,0.f,0.f,0.f), r4b = r4a, r4c = r4a, r4d = r4a;
    float r1 = 0.0f;

#define STEP(PL, PB, ACT) do { \
        float oM1 = dpp_shr1_f(o, 0.0f); \
        int   xM1 = dpp_shr1_i(ex, -(1 << 28)); \
        int   et  = (ex > xM1) ? ex : xM1; \
        int   dwn = ex - et; \
        float ao = ldexpf(o, dwn); \
        float ae = ldexpf(e, dwn); \
        float az = ldexpf(z, dwn); \
        float an = ldexpf(oM1, xM1 - et); \
        float uO = fmaf(an, allowF, ao + ae) * (PL); \
        float uE = (ae + an) * (PB); \
        float uZ = (az + ao) * (PB); \
        float mm = fmaxf(fmaxf(uO, uE), uZ); \
        int dd = (int)((__float_as_uint(mm) >> 23) & 255u) - 127; \
        bool act = (ACT); \
        o  = act ? ldexpf(uO, -dd) : o; \
        e  = act ? ldexpf(uE, -dd) : e; \
        z  = act ? ldexpf(uZ, -dd) : z; \
        ex = act ? (et + dd) : ex; \
    } while (0)

    for (int c = 0; c < 8; ++c) {
        // prefetch chunk c+1 raw (vmcnt consumed at end-of-chunk stores)
        if (c < 7) {
            const int tb = 1 + (c + 1) * 64;
            {
                int i = tid;            int tt = i >> 4, u4 = (i & 15) * 4;
                if (tb + tt < Tn) r4a = *(const float4*)(pm + (size_t)(tb + tt) * Un + u4);
                else r4a = make_float4(0.f,0.f,0.f,0.f);
            }
            {
                int i = tid + 256;      int tt = i >> 4, u4 = (i & 15) * 4;
                if (tb + tt < Tn) r4b = *(const float4*)(pm + (size_t)(tb + tt) * Un + u4);
                else r4b = make_float4(0.f,0.f,0.f,0.f);
            }
            {
                int i = tid + 512;      int tt = i >> 4, u4 = (i & 15) * 4;
                if (tb + tt < Tn) r4c = *(const float4*)(pm + (size_t)(tb + tt) * Un + u4);
                else r4c = make_float4(0.f,0.f,0.f,0.f);
            }
            {
                int i = tid + 768;      int tt = i >> 4, u4 = (i & 15) * 4;
                if (tb + tt < Tn) r4d = *(const float4*)(pm + (size_t)(tb + tt) * Un + u4);
                else r4d = make_float4(0.f,0.f,0.f,0.f);
            }
            if (tid < 64)
                r1 = (tb + tid < Tn) ? pm[(size_t)(tb + tid) * Un + 64] : 0.0f;
        }

        const float* buf = ls[c & 1];
        const int t0 = c * 64 + 1;      // timestep of row 0 in this chunk

        float plA[8], pbA[8], plB[8], pbB[8];
        #pragma unroll
        for (int j = 0; j < 8; ++j) {
            pbA[j] = buf[j * CS];
            plA[j] = buf[j * CS + 1 + l];
        }

        #pragma unroll
        for (int gg = 0; gg < 4; ++gg) {
            const int gA = 2 * gg, gB = 2 * gg + 1;
            // prefetch group gB into B
            #pragma unroll
            for (int j = 0; j < 8; ++j) {
                pbB[j] = buf[(gB * 8 + j) * CS];
                plB[j] = buf[(gB * 8 + j) * CS + 1 + l];
            }
            #pragma unroll
            for (int j = 0; j < 8; ++j)
                STEP(plA[j], pbA[j], (t0 + gA * 8 + j) < hl);
            // prefetch group gB+1 into A (skip past end)
            if (gg < 3) {
                #pragma unroll
                for (int j = 0; j < 8; ++j) {
                    pbA[j] = buf[((gB + 1) * 8 + j) * CS];
                    plA[j] = buf[((gB + 1) * 8 + j) * CS + 1 + l];
                }
            }
            #pragma unroll
            for (int j = 0; j < 8; ++j)
                STEP(plB[j], pbB[j], (t0 + gB * 8 + j) < hl);
        }

        if (c < 7) {
            float* dst = ls[(c + 1) & 1];
            { int i = tid;       int tt = i >> 4, u4 = (i & 15) * 4; *(float4*)(&dst[tt * CS + u4]) = r4a; }
            { int i = tid + 256; int tt = i >> 4, u4 = (i & 15) * 4; *(float4*)(&dst[tt * CS + u4]) = r4b; }
            { int i = tid + 512; int tt = i >> 4, u4 = (i & 15) * 4; *(float4*)(&dst[tt * CS + u4]) = r4c; }
            { int i = tid + 768; int tt = i >> 4, u4 = (i & 15) * 4; *(float4*)(&dst[tt * CS + u4]) = r4d; }
            if (tid < 64) dst[tid * CS + 64] = r1;
        }
        __syncthreads();
    }
#undef STEP

    if (tid < 64) { shO[l] = o; shE[l] = e; shZ[l] = z; shX[l] = ex; }
    __syncthreads();

    if (tid == 0) {
        int L = ylens[b];
        float vo = shO[L - 1]; int xo = shX[L - 1];     // alpha[2L-1]
        float ve; int xe;                                // alpha[2L]
        if (L == 64) { ve = shZ[63]; xe = shX[63]; }
        else         { ve = shE[L];  xe = shX[L]; }
        int em = (xo > xe) ? xo : xe;
        float s = ldexpf(vo, xo - em) + ldexpf(ve, xe - em);
        ll_out[b] = (lg2(s) + (float)em) * LN2;
    }
}

__global__ void finalize(const float* __restrict__ ll, float* __restrict__ out) {
    if (threadIdx.x == 0 && blockIdx.x == 0) {
        float s = 0.0f;
        #pragma unroll
        for (int b = 0; b < Bn; ++b) s += ll[b];
        out[0] = -s / (float)Bn;
    }
}

extern "C" void kernel_launch(void* const* d_in, const int* in_sizes, int n_in,
                              void* d_out, int out_size, void* d_ws, size_t ws_size,
                              hipStream_t stream) {
    const float* hs    = (const float*)d_in[0];
    const int*   hlens = (const int*)d_in[1];
    const int*   ys    = (const int*)d_in[2];
    const int*   ylens = (const int*)d_in[3];
    const float* W     = (const float*)d_in[4];
    const float* bias  = (const float*)d_in[5];
    float* out = (float*)d_out;

    char* ws = (char*)d_ws;
    unsigned short* hs_b = (unsigned short*)(ws);                       // 4,194,304 B
    unsigned short* w_b  = (unsigned short*)(ws + 4194304);             // 2,228,224 B
    unsigned short* wg_b = (unsigned short*)(ws + 6422528);             // 1,048,576 B
    float* glg2  = (float*)(ws + 7471104);                              // 2,621,440 B
    float* sep   = (float*)(ws + 10092544);                             // 1,114,112 B
    float* gbias = (float*)(ws + 11206656);                             //     8,192 B
    float* ll    = (float*)(ws + 11214848);                             //        64 B

    conv<<<1024, 256, 0, stream>>>(hs, W, bias, ys, hs_b, w_b, wg_b, gbias);
    gemm_se<<<dim3(64, NCB + 1), 256, 0, stream>>>(hs_b, w_b, wg_b, bias, gbias, sep, glg2);
    lse_norm<<<Mtot / 64, 256, 0, stream>>>(sep, glg2);   // glg2 -> linear probs in place
    ctc_fwd<<<Bn, 256, 0, stream>>>(glg2, ys, hlens, ylens, ll);
    finalize<<<1, 64, 0, stream>>>(ll, out);
}

// Round 15
// 142.942 us; speedup vs baseline: 1.0329x; 1.0008x over previous
//
#include <hip/hip_runtime.h>

constexpr int Bn = 16;
constexpr int Tn = 512;
constexpr int Dn = 256;
constexpr int Vn = 4233;
constexpr int Vp = 4352;   // V padded to 34*128
constexpr int Ln = 64;     // LMAX
constexpr int Un = 80;     // glg2/pmat row stride (65 used)
constexpr int CS = 68;     // ctc LDS row stride in floats
constexpr int NCB = 34;    // number of 128-wide vocab column blocks
constexpr int Mtot = Bn * Tn;  // 8192

#define LN2     0.6931471805599453f
#define INV_LN2 1.4426950408889634f

typedef __attribute__((ext_vector_type(8))) short short8;
typedef __attribute__((ext_vector_type(4))) float f32x4;

__device__ __forceinline__ float lg2(float x) { return __builtin_amdgcn_logf(x); }
__device__ __forceinline__ float ex2(float x) { return __builtin_amdgcn_exp2f(x); }

__device__ __forceinline__ unsigned short cvt_bf16(float f) {
    unsigned int u = __float_as_uint(f);
    u = (u + 0x7fffu + ((u >> 16) & 1u)) >> 16;
    return (unsigned short)u;
}

// async global->LDS, 16B per lane; LDS dest is wave-uniform base + lane*16
__device__ __forceinline__ void gl_lds16(const void* g, void* l) {
    __builtin_amdgcn_global_load_lds(
        (const __attribute__((address_space(1))) void*)g,
        (__attribute__((address_space(3))) void*)l,
        16, 0, 0);
}

// value from lane-1 (wave_shr:1); lane 0 takes `edge`
__device__ __forceinline__ float dpp_shr1_f(float v, float edge) {
    return __int_as_float(__builtin_amdgcn_update_dpp(
        __float_as_int(edge), __float_as_int(v), 0x138, 0xF, 0xF, false));
}
__device__ __forceinline__ int dpp_shr1_i(int v, int edge) {
    return __builtin_amdgcn_update_dpp(edge, v, 0x138, 0xF, 0xF, false);
}

// ---------------- conversion / gather prep ----------------
__global__ __launch_bounds__(256) void conv(
    const float* __restrict__ hs, const float* __restrict__ W,
    const float* __restrict__ bias, const int* __restrict__ ys,
    unsigned short* __restrict__ hs_b, unsigned short* __restrict__ w_b,
    unsigned short* __restrict__ wg_b, float* __restrict__ gbias)
{
    const int gid = blockIdx.x * 256 + threadIdx.x;
    const int stride = gridDim.x * 256;
    const float4* hs4 = (const float4*)hs;
    const float4* W4  = (const float4*)W;

    for (int i = gid; i < (Bn * Tn * Dn) / 4; i += stride) {
        float4 v = hs4[i];
        ushort4 o = make_ushort4(cvt_bf16(v.x), cvt_bf16(v.y), cvt_bf16(v.z), cvt_bf16(v.w));
        *(ushort4*)(&hs_b[i * 4]) = o;
    }
    for (int i = gid; i < Vp * (Dn / 4); i += stride) {
        int row = i >> 6;
        float4 v = make_float4(0.f, 0.f, 0.f, 0.f);
        if (row < Vn) v = W4[i];
        ushort4 o = make_ushort4(cvt_bf16(v.x), cvt_bf16(v.y), cvt_bf16(v.z), cvt_bf16(v.w));
        *(ushort4*)(&w_b[i * 4]) = o;
    }
    for (int i = gid; i < Bn * 128 * (Dn / 4); i += stride) {
        int b = i / (128 * (Dn / 4));
        int rem = i - b * (128 * (Dn / 4));
        int u = rem >> 6;
        int k4 = rem & 63;
        int v = (u == 0) ? 0 : ((u <= Ln) ? ys[b * Ln + u - 1] : -1);
        float4 val = make_float4(0.f, 0.f, 0.f, 0.f);
        if (v >= 0) val = W4[(size_t)v * (Dn / 4) + k4];
        ushort4 o = make_ushort4(cvt_bf16(val.x), cvt_bf16(val.y), cvt_bf16(val.z), cvt_bf16(val.w));
        *(ushort4*)(&wg_b[i * 4]) = o;
    }
    for (int i = gid; i < Bn * 128; i += stride) {
        int b = i >> 7;
        int u = i & 127;
        int v = (u == 0) ? 0 : ((u <= Ln) ? ys[b * Ln + u - 1] : -1);
        gbias[i] = (v >= 0) ? bias[v] : 0.0f;
    }
}

// ---------------- unified GEMM ----------------
// grid (64, 35). y<34: 128x128 vocab tile -> partial expsum sep[y][row].
// y==34: gathered-label tile (per-batch wg_b) -> raw log2-logits glg2.
// LDS XOR-swizzled (cg ^= row&7): MFMA reads conflict-free, staging contiguous.
__global__ __launch_bounds__(256) void gemm_se(
    const unsigned short* __restrict__ hs_b, const unsigned short* __restrict__ w_b,
    const unsigned short* __restrict__ wg_b, const float* __restrict__ bias,
    const float* __restrict__ gbias, float* __restrict__ sep,
    float* __restrict__ glg2)
{
    __shared__ __align__(16) short lsA[128 * 64];
    __shared__ __align__(16) short lsB[128 * 64];

    const int tid = threadIdx.x;
    const int lane = tid & 63;
    const int w = tid >> 6;
    const int lr = lane & 15;
    const int kq = lane >> 4;
    const int m0 = blockIdx.x * 128;
    const int mw = w * 32;
    const bool gather = (blockIdx.y == NCB);
    const int b = blockIdx.x >> 2;

    const int srow = lane >> 3;
    const int scg  = (lane & 7) ^ (srow & 7);
    const int scol = scg * 8;

    const unsigned short* Bp = gather ? (wg_b + (size_t)b * 128 * Dn)
                                      : (w_b + (size_t)blockIdx.y * 128 * Dn);

    f32x4 acc[2][8];
    #pragma unroll
    for (int mf = 0; mf < 2; ++mf)
        #pragma unroll
        for (int nf = 0; nf < 8; ++nf)
            acc[mf][nf] = (f32x4){0.f, 0.f, 0.f, 0.f};

    for (int ks = 0; ks < 4; ++ks) {
        const int k0 = ks * 64;
        __syncthreads();
        #pragma unroll
        for (int j = 0; j < 4; ++j) {
            int c = w * 4 + j;
            int row = c * 8 + srow;
            gl_lds16(hs_b + (size_t)(m0 + row) * Dn + k0 + scol, (char*)lsA + c * 1024);
            gl_lds16(Bp   + (size_t)row * Dn + k0 + scol,        (char*)lsB + c * 1024);
        }
        __syncthreads();

        #pragma unroll
        for (int sub = 0; sub < 2; ++sub) {
            short8 af[2], bf[8];
            #pragma unroll
            for (int mf = 0; mf < 2; ++mf) {
                int row = mw + mf * 16 + lr;
                int cg = (sub * 4 + kq) ^ (row & 7);
                af[mf] = *(const short8*)(&lsA[row * 64 + cg * 8]);
            }
            #pragma unroll
            for (int nf = 0; nf < 8; ++nf) {
                int row = nf * 16 + lr;
                int cg = (sub * 4 + kq) ^ (row & 7);
                bf[nf] = *(const short8*)(&lsB[row * 64 + cg * 8]);
            }
            #pragma unroll
            for (int mf = 0; mf < 2; ++mf)
                #pragma unroll
                for (int nf = 0; nf < 8; ++nf)
                    acc[mf][nf] = __builtin_amdgcn_mfma_f32_16x16x32_bf16(
                        af[mf], bf[nf], acc[mf][nf], 0, 0, 0);
        }
    }

    if (!gather) {
        const int n0 = blockIdx.y * 128;
        float bcol[8]; bool valid[8];
        #pragma unroll
        for (int nf = 0; nf < 8; ++nf) {
            int col = n0 + nf * 16 + lr;
            valid[nf] = (col < Vn);
            bcol[nf] = valid[nf] ? bias[col] : 0.0f;
        }
        #pragma unroll
        for (int mf = 0; mf < 2; ++mf) {
            #pragma unroll
            for (int r = 0; r < 4; ++r) {
                float s = 0.0f;
                #pragma unroll
                for (int nf = 0; nf < 8; ++nf)
                    if (valid[nf]) s += __expf(acc[mf][nf][r] + bcol[nf]);
                #pragma unroll
                for (int off = 1; off < 16; off <<= 1) s += __shfl_xor(s, off, 64);
                if (lr == 0)
                    sep[(size_t)blockIdx.y * Mtot + m0 + mw + mf * 16 + kq * 4 + r] = s;
            }
        }
    } else {
        #pragma unroll
        for (int mf = 0; mf < 2; ++mf) {
            #pragma unroll
            for (int nf = 0; nf < 5; ++nf) {
                int u = nf * 16 + lr;
                float gv = gbias[b * 128 + u];
                #pragma unroll
                for (int r = 0; r < 4; ++r) {
                    int g = m0 + mw + mf * 16 + kq * 4 + r;
                    glg2[(size_t)g * Un + u] = (acc[mf][nf][r] + gv) * INV_LN2;
                }
            }
        }
    }
}

// ---------------- lse + in-place normalize: glg2 <- exp2(glg2 - log2 sum) ----
__global__ __launch_bounds__(256) void lse_norm(
    const float* __restrict__ sep, float* __restrict__ glg2)
{
    __shared__ float sl[64];
    const int tid = threadIdx.x;
    const int g0 = blockIdx.x * 64;

    if (tid < 64) {
        float s = 0.0f;
        #pragma unroll
        for (int c = 0; c < NCB; ++c) s += sep[(size_t)c * Mtot + g0 + tid];
        sl[tid] = lg2(s);
    }
    __syncthreads();

    #pragma unroll
    for (int j = 0; j < 4; ++j) {
        int i = tid + j * 256;
        int row = i >> 4, u4 = (i & 15) * 4;
        float* p = glg2 + (size_t)(g0 + row) * Un + u4;
        float4 v = *(const float4*)p;
        float sub = sl[row];
        v.x = ex2(v.x - sub); v.y = ex2(v.y - sub);
        v.z = ex2(v.z - sub); v.w = ex2(v.w - sub);
        *(float4*)p = v;
    }
    if (tid < 64) {
        float* p = glg2 + (size_t)(g0 + tid) * Un + 64;
        *p = ex2(*p - sl[tid]);
    }
}

// ---------------- CTC forward recursion: 2-step composite ----------------
// Linear f32 mantissa + per-lane int exponent. Lane l: e=alpha[2l],
// o=alpha[2l+1]; z=alpha[128] (lane 63). Two timesteps fused per iteration:
// the bandwidth-5 composite's 13 coefficients depend only on p's (off-chain);
// the dependent chain advances 2 steps per align+fma-tree+renorm.
// No register arrays anywhere (scratch-proof). hl==Tn fast path unpredicated.
__global__ __launch_bounds__(256) void ctc_fwd(
    const float* __restrict__ pmat, const int* __restrict__ ys,
    const int* __restrict__ hlens, const int* __restrict__ ylens,
    float* __restrict__ ll_out)
{
    __shared__ float ls[2][64 * CS + 4];
    __shared__ float shO[64], shE[64], shZ[64];
    __shared__ int   shX[64];

    const int b = blockIdx.x;
    const int tid = threadIdx.x;
    const int l = tid & 63;

    const int hl = hlens[b];
    int yl  = ys[b * Ln + l];
    int ylm = (l >= 1) ? ys[b * Ln + l - 1] : -1;
    const float aF  = ((l >= 1) && (yl != ylm)) ? 1.0f : 0.0f;
    const float amF = dpp_shr1_f(aF, 0.0f);      // allow_{l-1}

    const float* pm = pmat + (size_t)b * Tn * Un;

    // stage chunk 0 (row tt <-> t = 1 + tt)
    #pragma unroll
    for (int j = 0; j < 4; ++j) {
        int i = tid + j * 256;
        int tt = i >> 4, u4 = (i & 15) * 4;
        *(float4*)(&ls[0][tt * CS + u4]) = *(const float4*)(pm + (size_t)(1 + tt) * Un + u4);
    }
    if (tid < 64) ls[0][tid * CS + 64] = pm[(size_t)(1 + tid) * Un + 64];
    __syncthreads();

    // t=0 init
    float o = (l == 0) ? pm[1] : 0.0f;
    float e = (l == 0) ? pm[0] : 0.0f;
    float z = 0.0f;
    int ex = 0;

    float4 r4a = make_float4(0.f,0.f,0.f,0.f), r4b = r4a, r4c = r4a, r4d = r4a;
    float r1 = 0.0f;

// one composite 2-step update; Joff = chunk-local row of first step
#define PAIR2(Joff) do { \
        float q  = buf[(Joff) * CS]; \
        float Q  = buf[((Joff) + 1) * CS]; \
        float r  = buf[(Joff) * CS + 1 + l]; \
        float R  = buf[((Joff) + 1) * CS + 1 + l]; \
        float rm1 = dpp_shr1_f(r, 0.0f); \
        float Qq = Q * q; \
        float C2 = Q * (q + rm1); \
        float C3 = Q * rm1; \
        float C4 = C3 * amF; \
        float D1 = R * r; \
        float D2 = R * (r + q); \
        float D3 = R * fmaf(aF, r + rm1, q); \
        float D4 = (R * rm1) * aF; \
        float D5 = D4 * amF; \
        float E2 = Q * (q + r); \
        float E3 = Q * r; \
        float E4 = E3 * aF; \
        float om1 = dpp_shr1_f(o, 0.0f); \
        float em1 = dpp_shr1_f(e, 0.0f); \
        int   xm1 = dpp_shr1_i(ex, -(1 << 28)); \
        float om2 = dpp_shr1_f(om1, 0.0f); \
        int   xm2 = dpp_shr1_i(xm1, -(1 << 28)); \
        int et0 = (xm1 > xm2) ? xm1 : xm2; \
        int et  = (ex > et0) ? ex : et0; \
        int d0 = ex - et, d1 = xm1 - et, d2 = xm2 - et; \
        float sO  = ldexpf(o, d0), sE = ldexpf(e, d0), sZ = ldexpf(z, d0); \
        float sO1 = ldexpf(om1, d1), sE1 = ldexpf(em1, d1); \
        float sO2 = ldexpf(om2, d2); \
        float nE = fmaf(Qq, sE, C2 * sO1) + fmaf(C3, sE1, C4 * sO2); \
        float nO = (fmaf(D1, sO, D2 * sE) + fmaf(D3, sO1, D4 * sE1)) + D5 * sO2; \
        float nZ = fmaf(Qq, sZ, E2 * sO) + fmaf(E3, sE, E4 * sO1); \
        float mm = fmaxf(fmaxf(nO, nE), nZ); \
        int dd = (int)((__float_as_uint(mm) >> 23) & 255u) - 127; \
        o = ldexpf(nO, -dd); e = ldexpf(nE, -dd); z = ldexpf(nZ, -dd); \
        ex = et + dd; \
    } while (0)

// one plain step at chunk-local row Joff
#define STEP1(Joff) do { \
        float q = buf[(Joff) * CS]; \
        float r = buf[(Joff) * CS + 1 + l]; \
        float om1 = dpp_shr1_f(o, 0.0f); \
        int   xm1 = dpp_shr1_i(ex, -(1 << 28)); \
        int et = (ex > xm1) ? ex : xm1; \
        int d0 = ex - et, d1 = xm1 - et; \
        float sO = ldexpf(o, d0), sE = ldexpf(e, d0), sZ = ldexpf(z, d0); \
        float sO1 = ldexpf(om1, d1); \
        float nO = (sO + fmaf(aF, sO1, sE)) * r; \
        float nE = (sE + sO1) * q; \
        float nZ = (sZ + sO) * q; \
        float mm = fmaxf(fmaxf(nO, nE), nZ); \
        int dd = (int)((__float_as_uint(mm) >> 23) & 255u) - 127; \
        o = ldexpf(nO, -dd); e = ldexpf(nE, -dd); z = ldexpf(nZ, -dd); \
        ex = et + dd; \
    } while (0)

    for (int c = 0; c < 8; ++c) {
        // prefetch chunk c+1 raw (vmcnt consumed at end-of-chunk stores)
        if (c < 7) {
            const int tb = 1 + (c + 1) * 64;
            {
                int i = tid;            int tt = i >> 4, u4 = (i & 15) * 4;
                if (tb + tt < Tn) r4a = *(const float4*)(pm + (size_t)(tb + tt) * Un + u4);
                else r4a = make_float4(0.f,0.f,0.f,0.f);
            }
            {
                int i = tid + 256;      int tt = i >> 4, u4 = (i & 15) * 4;
                if (tb + tt < Tn) r4b = *(const float4*)(pm + (size_t)(tb + tt) * Un + u4);
                else r4b = make_float4(0.f,0.f,0.f,0.f);
            }
            {
                int i = tid + 512;      int tt = i >> 4, u4 = (i & 15) * 4;
                if (tb + tt < Tn) r4c = *(const float4*)(pm + (size_t)(tb + tt) * Un + u4);
                else r4c = make_float4(0.f,0.f,0.f,0.f);
            }
            {
                int i = tid + 768;      int tt = i >> 4, u4 = (i & 15) * 4;
                if (tb + tt < Tn) r4d = *(const float4*)(pm + (size_t)(tb + tt) * Un + u4);
                else r4d = make_float4(0.f,0.f,0.f,0.f);
            }
            if (tid < 64)
                r1 = (tb + tid < Tn) ? pm[(size_t)(tb + tid) * Un + 64] : 0.0f;
        }

        const float* buf = ls[c & 1];

        if (c < 7) {
            if (hl >= (c + 1) * 64 + 1) {
                // fully active chunk: 32 unpredicated composite pairs
                #pragma unroll
                for (int j = 0; j < 32; ++j) PAIR2(2 * j);
            } else {
                // generic tail (never hit when hl == Tn)
                #pragma unroll 1
                for (int j = 0; j < 32; ++j) {
                    int t = c * 64 + 1 + 2 * j;
                    if (t + 1 < hl)      PAIR2(2 * j);
                    else if (t < hl)     STEP1(2 * j);
                }
            }
        } else {
            if (hl >= Tn) {
                // 31 pairs (t=449..510) + single final step t=511
                #pragma unroll
                for (int j = 0; j < 31; ++j) PAIR2(2 * j);
                STEP1(62);
            } else {
                #pragma unroll 1
                for (int j = 0; j < 31; ++j) {
                    int t = 449 + 2 * j;
                    if (t + 1 < hl)      PAIR2(2 * j);
                    else if (t < hl)     STEP1(2 * j);
                }
                if (511 < hl) STEP1(62);
            }
        }

        if (c < 7) {
            float* dst = ls[(c + 1) & 1];
            { int i = tid;       int tt = i >> 4, u4 = (i & 15) * 4; *(float4*)(&dst[tt * CS + u4]) = r4a; }
            { int i = tid + 256; int tt = i >> 4, u4 = (i & 15) * 4; *(float4*)(&dst[tt * CS + u4]) = r4b; }
            { int i = tid + 512; int tt = i >> 4, u4 = (i & 15) * 4; *(float4*)(&dst[tt * CS + u4]) = r4c; }
            { int i = tid + 768; int tt = i >> 4, u4 = (i & 15) * 4; *(float4*)(&dst[tt * CS + u4]) = r4d; }
            if (tid < 64) dst[tid * CS + 64] = r1;
        }
        __syncthreads();
    }
#undef PAIR2
#undef STEP1

    if (tid < 64) { shO[l] = o; shE[l] = e; shZ[l] = z; shX[l] = ex; }
    __syncthreads();

    if (tid == 0) {
        int L = ylens[b];
        float vo = shO[L - 1]; int xo = shX[L - 1];     // alpha[2L-1]
        float ve; int xe;                                // alpha[2L]
        if (L == 64) { ve = shZ[63]; xe = shX[63]; }
        else         { ve = shE[L];  xe = shX[L]; }
        int em = (xo > xe) ? xo : xe;
        float s = ldexpf(vo, xo - em) + ldexpf(ve, xe - em);
        ll_out[b] = (lg2(s) + (float)em) * LN2;
    }
}

__global__ void finalize(const float* __restrict__ ll, float* __restrict__ out) {
    if (threadIdx.x == 0 && blockIdx.x == 0) {
        float s = 0.0f;
        #pragma unroll
        for (int b = 0; b < Bn; ++b) s += ll[b];
        out[0] = -s / (float)Bn;
    }
}

extern "C" void kernel_launch(void* const* d_in, const int* in_sizes, int n_in,
                              void* d_out, int out_size, void* d_ws, size_t ws_size,
                              hipStream_t stream) {
    const float* hs    = (const float*)d_in[0];
    const int*   hlens = (const int*)d_in[1];
    const int*   ys    = (const int*)d_in[2];
    const int*   ylens = (const int*)d_in[3];
    const float* W     = (const float*)d_in[4];
    const float* bias  = (const float*)d_in[5];
    float* out = (float*)d_out;

    char* ws = (char*)d_ws;
    unsigned short* hs_b = (unsigned short*)(ws);                       // 4,194,304 B
    unsigned short* w_b  = (unsigned short*)(ws + 4194304);             // 2,228,224 B
    unsigned short* wg_b = (unsigned short*)(ws + 6422528);             // 1,048,576 B
    float* glg2  = (float*)(ws + 7471104);                              // 2,621,440 B
    float* sep   = (float*)(ws + 10092544);                             // 1,114,112 B
    float* gbias = (float*)(ws + 11206656);                             //     8,192 B
    float* ll    = (float*)(ws + 11214848);                             //        64 B

    conv<<<1024, 256, 0, stream>>>(hs, W, bias, ys, hs_b, w_b, wg_b, gbias);
    gemm_se<<<dim3(64, NCB + 1), 256, 0, stream>>>(hs_b, w_b, wg_b, bias, gbias, sep, glg2);
    lse_norm<<<Mtot / 64, 256, 0, stream>>>(sep, glg2);   // glg2 -> linear probs in place
    ctc_fwd<<<Bn, 256, 0, stream>>>(glg2, ys, hlens, ylens, ll);
    finalize<<<1, 64, 0, stream>>>(ll, out);
}

// Round 17
// 126.567 us; speedup vs baseline: 1.1666x; 1.1294x over previous
//
#include <hip/hip_runtime.h>

constexpr int Bn = 16;
constexpr int Tn = 512;
constexpr int Dn = 256;
constexpr int Vn = 4233;
constexpr int Vp = 4352;   // V padded to 34*128 (rows 4233.. are zeros)
constexpr int Ln = 64;     // LMAX
constexpr int Un = 80;     // glg2/pmat row stride (65 used)
constexpr int CS = 68;     // ctc LDS row stride in floats
constexpr int NCB = 34;    // number of 128-wide vocab column blocks
constexpr int Mtot = Bn * Tn;  // 8192

#define LN2     0.6931471805599453f
#define INV_LN2 1.4426950408889634f

typedef __attribute__((ext_vector_type(8))) short short8;
typedef __attribute__((ext_vector_type(4))) float f32x4;

__device__ __forceinline__ float lg2(float x) { return __builtin_amdgcn_logf(x); }
__device__ __forceinline__ float ex2(float x) { return __builtin_amdgcn_exp2f(x); }

__device__ __forceinline__ unsigned short cvt_bf16(float f) {
    unsigned int u = __float_as_uint(f);
    u = (u + 0x7fffu + ((u >> 16) & 1u)) >> 16;
    return (unsigned short)u;
}

// async global->LDS, 16B per lane; LDS dest contiguous per lane, global addr per-lane
__device__ __forceinline__ void gl_lds16(const void* g, void* l) {
    __builtin_amdgcn_global_load_lds(
        (const __attribute__((address_space(1))) void*)g,
        (__attribute__((address_space(3))) void*)l,
        16, 0, 0);
}

// value from lane-1 (wave_shr:1); lane 0 takes `edge`
__device__ __forceinline__ float dpp_shr1_f(float v, float edge) {
    return __int_as_float(__builtin_amdgcn_update_dpp(
        __float_as_int(edge), __float_as_int(v), 0x138, 0xF, 0xF, false));
}
__device__ __forceinline__ int dpp_shr1_i(int v, int edge) {
    return __builtin_amdgcn_update_dpp(edge, v, 0x138, 0xF, 0xF, false);
}

// ---------------- conversion prep (zeroes d_out) ----------------
__global__ __launch_bounds__(256) void conv(
    const float* __restrict__ hs, const float* __restrict__ W,
    const float* __restrict__ bias, const int* __restrict__ ys,
    unsigned short* __restrict__ hs_b, unsigned short* __restrict__ w_b,
    float* __restrict__ gbias, float* __restrict__ out)
{
    const int gid = blockIdx.x * 256 + threadIdx.x;
    const int stride = gridDim.x * 256;
    const float4* hs4 = (const float4*)hs;
    const float4* W4  = (const float4*)W;

    if (gid == 0) out[0] = 0.0f;   // atomic target for ctc_fwd

    for (int i = gid; i < (Bn * Tn * Dn) / 4; i += stride) {
        float4 v = hs4[i];
        ushort4 o = make_ushort4(cvt_bf16(v.x), cvt_bf16(v.y), cvt_bf16(v.z), cvt_bf16(v.w));
        *(ushort4*)(&hs_b[i * 4]) = o;
    }
    for (int i = gid; i < Vp * (Dn / 4); i += stride) {
        int row = i >> 6;
        float4 v = make_float4(0.f, 0.f, 0.f, 0.f);
        if (row < Vn) v = W4[i];
        ushort4 o = make_ushort4(cvt_bf16(v.x), cvt_bf16(v.y), cvt_bf16(v.z), cvt_bf16(v.w));
        *(ushort4*)(&w_b[i * 4]) = o;
    }
    for (int i = gid; i < Bn * 128; i += stride) {
        int b = i >> 7;
        int u = i & 127;
        int v = (u == 0) ? 0 : ((u <= Ln) ? ys[b * Ln + u - 1] : -1);
        gbias[i] = (v >= 0) ? bias[v] : 0.0f;
    }
}

// ---------------- unified GEMM ----------------
// grid (64, 35). y<34: 128x128 vocab tile -> partial expsum sep[y][row].
// y==34: gathered-label tile -> raw log2-logits glg2 (B staged directly from
// w_b via per-lane indirect global addresses; pad labels hit w_b zero rows).
// LDS XOR-swizzled (cg ^= row&7).
__global__ __launch_bounds__(256) void gemm_se(
    const unsigned short* __restrict__ hs_b, const unsigned short* __restrict__ w_b,
    const int* __restrict__ ys, const float* __restrict__ bias,
    const float* __restrict__ gbias, float* __restrict__ sep,
    float* __restrict__ glg2)
{
    __shared__ __align__(16) short lsA[128 * 64];
    __shared__ __align__(16) short lsB[128 * 64];

    const int tid = threadIdx.x;
    const int lane = tid & 63;
    const int w = tid >> 6;
    const int lr = lane & 15;
    const int kq = lane >> 4;
    const int m0 = blockIdx.x * 128;
    const int mw = w * 32;
    const bool gather = (blockIdx.y == NCB);
    const int b = blockIdx.x >> 2;

    const int srow = lane >> 3;
    const int scg  = (lane & 7) ^ (srow & 7);
    const int scol = scg * 8;

    const unsigned short* bptr[4];
    #pragma unroll
    for (int j = 0; j < 4; ++j) {
        int c = w * 4 + j;
        int row = c * 8 + srow;
        int v;
        if (gather) {
            if (row == 0) v = 0;
            else if (row <= Ln) v = ys[b * Ln + row - 1];
            else v = Vn + 32;                 // zero pad row of w_b
        } else {
            v = blockIdx.y * 128 + row;
        }
        bptr[j] = w_b + (size_t)v * Dn + scol;
    }

    f32x4 acc[2][8];
    #pragma unroll
    for (int mf = 0; mf < 2; ++mf)
        #pragma unroll
        for (int nf = 0; nf < 8; ++nf)
            acc[mf][nf] = (f32x4){0.f, 0.f, 0.f, 0.f};

    for (int ks = 0; ks < 4; ++ks) {
        const int k0 = ks * 64;
        __syncthreads();
        #pragma unroll
        for (int j = 0; j < 4; ++j) {
            int c = w * 4 + j;
            int row = c * 8 + srow;
            gl_lds16(hs_b + (size_t)(m0 + row) * Dn + k0 + scol, (char*)lsA + c * 1024);
            gl_lds16(bptr[j] + k0,                               (char*)lsB + c * 1024);
        }
        __syncthreads();

        #pragma unroll
        for (int sub = 0; sub < 2; ++sub) {
            short8 af[2], bf[8];
            #pragma unroll
            for (int mf = 0; mf < 2; ++mf) {
                int row = mw + mf * 16 + lr;
                int cg = (sub * 4 + kq) ^ (row & 7);
                af[mf] = *(const short8*)(&lsA[row * 64 + cg * 8]);
            }
            #pragma unroll
            for (int nf = 0; nf < 8; ++nf) {
                int row = nf * 16 + lr;
                int cg = (sub * 4 + kq) ^ (row & 7);
                bf[nf] = *(const short8*)(&lsB[row * 64 + cg * 8]);
            }
            #pragma unroll
            for (int mf = 0; mf < 2; ++mf)
                #pragma unroll
                for (int nf = 0; nf < 8; ++nf)
                    acc[mf][nf] = __builtin_amdgcn_mfma_f32_16x16x32_bf16(
                        af[mf], bf[nf], acc[mf][nf], 0, 0, 0);
        }
    }

    if (!gather) {
        const int n0 = blockIdx.y * 128;
        float bcol[8]; bool valid[8];
        #pragma unroll
        for (int nf = 0; nf < 8; ++nf) {
            int col = n0 + nf * 16 + lr;
            valid[nf] = (col < Vn);
            bcol[nf] = valid[nf] ? bias[col] : 0.0f;
        }
        #pragma unroll
        for (int mf = 0; mf < 2; ++mf) {
            #pragma unroll
            for (int r = 0; r < 4; ++r) {
                float s = 0.0f;
                #pragma unroll
                for (int nf = 0; nf < 8; ++nf)
                    if (valid[nf]) s += __expf(acc[mf][nf][r] + bcol[nf]);
                #pragma unroll
                for (int off = 1; off < 16; off <<= 1) s += __shfl_xor(s, off, 64);
                if (lr == 0)
                    sep[(size_t)blockIdx.y * Mtot + m0 + mw + mf * 16 + kq * 4 + r] = s;
            }
        }
    } else {
        #pragma unroll
        for (int mf = 0; mf < 2; ++mf) {
            #pragma unroll
            for (int nf = 0; nf < 5; ++nf) {
                int u = nf * 16 + lr;
                float gv = gbias[b * 128 + u];
                #pragma unroll
                for (int r = 0; r < 4; ++r) {
                    int g = m0 + mw + mf * 16 + kq * 4 + r;
                    glg2[(size_t)g * Un + u] = (acc[mf][nf][r] + gv) * INV_LN2;
                }
            }
        }
    }
}

// ---------------- lse + in-place normalize: glg2 <- exp2(glg2 - log2 sum) ----
__global__ __launch_bounds__(256) void lse_norm(
    const float* __restrict__ sep, float* __restrict__ glg2)
{
    __shared__ float sl[64];
    const int tid = threadIdx.x;
    const int g0 = blockIdx.x * 64;

    if (tid < 64) {
        float s = 0.0f;
        #pragma unroll
        for (int c = 0; c < NCB; ++c) s += sep[(size_t)c * Mtot + g0 + tid];
        sl[tid] = lg2(s);
    }
    __syncthreads();

    #pragma unroll
    for (int j = 0; j < 4; ++j) {
        int i = tid + j * 256;
        int row = i >> 4, u4 = (i & 15) * 4;
        float* p = glg2 + (size_t)(g0 + row) * Un + u4;
        float4 v = *(const float4*)p;
        float sub = sl[row];
        v.x = ex2(v.x - sub); v.y = ex2(v.y - sub);
        v.z = ex2(v.z - sub); v.w = ex2(v.w - sub);
        *(float4*)p = v;
    }
    if (tid < 64) {
        float* p = glg2 + (size_t)(g0 + tid) * Un + 64;
        *p = ex2(*p - sl[tid]);
    }
}

// ---------------- CTC forward recursion ----------------
// Linear f32 mantissa + per-lane int storage scale, renorm every 4 steps.
// REVISED renorm (round-16 inf fix): nonzero lanes keep their own exact scale
// (mantissa restarts in [1,2)); zero lanes ADOPT the left neighbor's scale.
// => incoming-mass shift dn is 0 / negative at the frontier (never upshifted),
// and nonzero-lane dn is bounded by the adjacent-state feed-path ratio (~36
// bits) -> an <= 2^40, no overflow; post-renorm mantissa in [1,2) -> no
// in-window underflow. Lane l: e=alpha[2l], o=alpha[2l+1]; z=alpha[128].
__global__ __launch_bounds__(256) void ctc_fwd(
    const float* __restrict__ pmat, const int* __restrict__ ys,
    const int* __restrict__ hlens, const int* __restrict__ ylens,
    float* __restrict__ out)
{
    __shared__ float ls[2][64 * CS + 4];
    __shared__ float shO[64], shE[64], shZ[64];
    __shared__ int   shX[64];

    const int b = blockIdx.x;
    const int tid = threadIdx.x;
    const int l = tid & 63;

    const int hl = hlens[b];
    int yl  = ys[b * Ln + l];
    int ylm = (l >= 1) ? ys[b * Ln + l - 1] : -1;
    const float aF = ((l >= 1) && (yl != ylm)) ? 1.0f : 0.0f;

    const float* pm = pmat + (size_t)b * Tn * Un;

    // stage chunk 0 (row tt <-> t = 1 + tt)
    #pragma unroll
    for (int j = 0; j < 4; ++j) {
        int i = tid + j * 256;
        int tt = i >> 4, u4 = (i & 15) * 4;
        *(float4*)(&ls[0][tt * CS + u4]) = *(const float4*)(pm + (size_t)(1 + tt) * Un + u4);
    }
    if (tid < 64) ls[0][tid * CS + 64] = pm[(size_t)(1 + tid) * Un + 64];
    __syncthreads();

    // t=0 init (all lanes scale 0)
    float o = (l == 0) ? pm[1] : 0.0f;
    float e = (l == 0) ? pm[0] : 0.0f;
    float z = 0.0f;
    int ex = 0;     // storage scale: value = mantissa * 2^ex
    int dn = 0;     // neighbor scale minus own scale (window-constant)

    float4 r4a = make_float4(0.f,0.f,0.f,0.f), r4b = r4a, r4c = r4a, r4d = r4a;
    float r1 = 0.0f;

// renorm + scale policy (value-preserving):
//  nonzero: et = own exT (mantissa in [1,2)); zero: et = left neighbor's exT
#define RENORM do { \
        float mm = fmaxf(fmaxf(o, e), z); \
        bool nz = (mm > 0.0f); \
        int dd = nz ? ((int)((__float_as_uint(mm) >> 23) & 255u) - 127) : 0; \
        o = ldexpf(o, -dd); e = ldexpf(e, -dd); z = ldexpf(z, -dd); \
        int exT = ex + dd; \
        int xm1 = dpp_shr1_i(exT, -(1 << 28)); \
        int et = nz ? exT : xm1; \
        ex = et; \
        int xet = dpp_shr1_i(et, -(1 << 28)); \
        dn = xet - ex; \
    } while (0)

// one step, scales frozen; Joff = chunk-local row
#define STEPF(Joff) do { \
        float q = buf[(Joff) * CS]; \
        float r = buf[(Joff) * CS + 1 + l]; \
        float om1 = dpp_shr1_f(o, 0.0f); \
        float an  = ldexpf(om1, dn); \
        float nO = fmaf(aF, an, o + e) * r; \
        float nE = (e + an) * q; \
        float nZ = (z + o) * q; \
        o = nO; e = nE; z = nZ; \
    } while (0)

// predicated step for partial chunks (renorm each step, value-preserving)
#define STEPS(Joff, ACT) do { \
        RENORM; \
        float q = buf[(Joff) * CS]; \
        float r = buf[(Joff) * CS + 1 + l]; \
        float om1 = dpp_shr1_f(o, 0.0f); \
        float an  = ldexpf(om1, dn); \
        float nO = fmaf(aF, an, o + e) * r; \
        float nE = (e + an) * q; \
        float nZ = (z + o) * q; \
        bool act = (ACT); \
        o = act ? nO : o; e = act ? nE : e; z = act ? nZ : z; \
    } while (0)

    for (int c = 0; c < 8; ++c) {
        if (c < 7) {
            const int tb = 1 + (c + 1) * 64;
            { int i = tid;       int tt = i >> 4, u4 = (i & 15) * 4;
              r4a = (tb + tt < Tn) ? *(const float4*)(pm + (size_t)(tb + tt) * Un + u4) : make_float4(0.f,0.f,0.f,0.f); }
            { int i = tid + 256; int tt = i >> 4, u4 = (i & 15) * 4;
              r4b = (tb + tt < Tn) ? *(const float4*)(pm + (size_t)(tb + tt) * Un + u4) : make_float4(0.f,0.f,0.f,0.f); }
            { int i = tid + 512; int tt = i >> 4, u4 = (i & 15) * 4;
              r4c = (tb + tt < Tn) ? *(const float4*)(pm + (size_t)(tb + tt) * Un + u4) : make_float4(0.f,0.f,0.f,0.f); }
            { int i = tid + 768; int tt = i >> 4, u4 = (i & 15) * 4;
              r4d = (tb + tt < Tn) ? *(const float4*)(pm + (size_t)(tb + tt) * Un + u4) : make_float4(0.f,0.f,0.f,0.f); }
            if (tid < 64)
                r1 = (tb + tid < Tn) ? pm[(size_t)(tb + tid) * Un + 64] : 0.0f;
        }

        const float* buf = ls[c & 1];

        if (c < 7) {
            if (hl >= (c + 1) * 64 + 1) {
                #pragma unroll
                for (int ww = 0; ww < 16; ++ww) {
                    RENORM;
                    STEPF(4 * ww);
                    STEPF(4 * ww + 1);
                    STEPF(4 * ww + 2);
                    STEPF(4 * ww + 3);
                }
            } else {
                #pragma unroll 1
                for (int j = 0; j < 64; ++j)
                    STEPS(j, (c * 64 + 1 + j) < hl);
            }
        } else {
            if (hl >= Tn) {
                #pragma unroll
                for (int ww = 0; ww < 15; ++ww) {
                    RENORM;
                    STEPF(4 * ww);
                    STEPF(4 * ww + 1);
                    STEPF(4 * ww + 2);
                    STEPF(4 * ww + 3);
                }
                RENORM;
                STEPF(60); STEPF(61); STEPF(62);
            } else {
                #pragma unroll 1
                for (int j = 0; j < 63; ++j)
                    STEPS(j, (449 + j) < hl);
            }
        }

        if (c < 7) {
            float* dst = ls[(c + 1) & 1];
            { int i = tid;       int tt = i >> 4, u4 = (i & 15) * 4; *(float4*)(&dst[tt * CS + u4]) = r4a; }
            { int i = tid + 256; int tt = i >> 4, u4 = (i & 15) * 4; *(float4*)(&dst[tt * CS + u4]) = r4b; }
            { int i = tid + 512; int tt = i >> 4, u4 = (i & 15) * 4; *(float4*)(&dst[tt * CS + u4]) = r4c; }
            { int i = tid + 768; int tt = i >> 4, u4 = (i & 15) * 4; *(float4*)(&dst[tt * CS + u4]) = r4d; }
            if (tid < 64) dst[tid * CS + 64] = r1;
        }
        __syncthreads();
    }
#undef RENORM
#undef STEPF
#undef STEPS

    if (tid < 64) { shO[l] = o; shE[l] = e; shZ[l] = z; shX[l] = ex; }
    __syncthreads();

    if (tid == 0) {
        int L = ylens[b];
        float vo = shO[L - 1]; int xo = shX[L - 1];     // alpha[2L-1]
        float ve; int xe;                                // alpha[2L]
        if (L == 64) { ve = shZ[63]; xe = shX[63]; }
        else         { ve = shE[L];  xe = shX[L]; }
        int em = (xo > xe) ? xo : xe;
        float s = ldexpf(vo, xo - em) + ldexpf(ve, xe - em);
        float ll = (lg2(s) + (float)em) * LN2;
        atomicAdd(out, -ll / (float)Bn);
    }
}

extern "C" void kernel_launch(void* const* d_in, const int* in_sizes, int n_in,
                              void* d_out, int out_size, void* d_ws, size_t ws_size,
                              hipStream_t stream) {
    const float* hs    = (const float*)d_in[0];
    const int*   hlens = (const int*)d_in[1];
    const int*   ys    = (const int*)d_in[2];
    const int*   ylens = (const int*)d_in[3];
    const float* W     = (const float*)d_in[4];
    const float* bias  = (const float*)d_in[5];
    float* out = (float*)d_out;

    char* ws = (char*)d_ws;
    unsigned short* hs_b = (unsigned short*)(ws);                       // 4,194,304 B
    unsigned short* w_b  = (unsigned short*)(ws + 4194304);             // 2,228,224 B
    float* glg2  = (float*)(ws + 6422528);                              // 2,621,440 B
    float* sep   = (float*)(ws + 9043968);                              // 1,114,112 B
    float* gbias = (float*)(ws + 10158080);                             //     8,192 B

    conv<<<1024, 256, 0, stream>>>(hs, W, bias, ys, hs_b, w_b, gbias, out);
    gemm_se<<<dim3(64, NCB + 1), 256, 0, stream>>>(hs_b, w_b, ys, bias, gbias, sep, glg2);
    lse_norm<<<Mtot / 64, 256, 0, stream>>>(sep, glg2);   // glg2 -> linear probs in place
    ctc_fwd<<<Bn, 256, 0, stream>>>(glg2, ys, hlens, ylens, out);
}

// Round 18
// 125.710 us; speedup vs baseline: 1.1745x; 1.0068x over previous
//
#include <hip/hip_runtime.h>

constexpr int Bn = 16;
constexpr int Tn = 512;
constexpr int Dn = 256;
constexpr int Vn = 4233;
constexpr int Vp = 4352;   // V padded to 34*128 (rows 4233.. are zeros)
constexpr int Ln = 64;     // LMAX
constexpr int Un = 80;     // glg2/pmat row stride (65 used)
constexpr int CS = 68;     // ctc LDS row stride in floats
constexpr int NCB = 34;    // number of 128-wide vocab column blocks
constexpr int Mtot = Bn * Tn;  // 8192

#define LN2     0.6931471805599453f
#define INV_LN2 1.4426950408889634f

typedef __attribute__((ext_vector_type(8))) short short8;
typedef __attribute__((ext_vector_type(4))) float f32x4;

__device__ __forceinline__ float lg2(float x) { return __builtin_amdgcn_logf(x); }
__device__ __forceinline__ float ex2(float x) { return __builtin_amdgcn_exp2f(x); }

__device__ __forceinline__ unsigned short cvt_bf16(float f) {
    unsigned int u = __float_as_uint(f);
    u = (u + 0x7fffu + ((u >> 16) & 1u)) >> 16;
    return (unsigned short)u;
}

// async global->LDS, 16B per lane; LDS dest contiguous per lane, global addr per-lane
__device__ __forceinline__ void gl_lds16(const void* g, void* l) {
    __builtin_amdgcn_global_load_lds(
        (const __attribute__((address_space(1))) void*)g,
        (__attribute__((address_space(3))) void*)l,
        16, 0, 0);
}

// value from lane-1 (wave_shr:1); lane 0 takes `edge`
__device__ __forceinline__ float dpp_shr1_f(float v, float edge) {
    return __int_as_float(__builtin_amdgcn_update_dpp(
        __float_as_int(edge), __float_as_int(v), 0x138, 0xF, 0xF, false));
}
__device__ __forceinline__ int dpp_shr1_i(int v, int edge) {
    return __builtin_amdgcn_update_dpp(edge, v, 0x138, 0xF, 0xF, false);
}

// ---------------- conversion prep (zeroes d_out) ----------------
__global__ __launch_bounds__(256) void conv(
    const float* __restrict__ hs, const float* __restrict__ W,
    const float* __restrict__ bias, const int* __restrict__ ys,
    unsigned short* __restrict__ hs_b, unsigned short* __restrict__ w_b,
    float* __restrict__ gbias, float* __restrict__ out)
{
    const int gid = blockIdx.x * 256 + threadIdx.x;
    const int stride = gridDim.x * 256;
    const float4* hs4 = (const float4*)hs;
    const float4* W4  = (const float4*)W;

    if (gid == 0) out[0] = 0.0f;   // atomic target for ctc_fwd

    for (int i = gid; i < (Bn * Tn * Dn) / 4; i += stride) {
        float4 v = hs4[i];
        ushort4 o = make_ushort4(cvt_bf16(v.x), cvt_bf16(v.y), cvt_bf16(v.z), cvt_bf16(v.w));
        *(ushort4*)(&hs_b[i * 4]) = o;
    }
    for (int i = gid; i < Vp * (Dn / 4); i += stride) {
        int row = i >> 6;
        float4 v = make_float4(0.f, 0.f, 0.f, 0.f);
        if (row < Vn) v = W4[i];
        ushort4 o = make_ushort4(cvt_bf16(v.x), cvt_bf16(v.y), cvt_bf16(v.z), cvt_bf16(v.w));
        *(ushort4*)(&w_b[i * 4]) = o;
    }
    for (int i = gid; i < Bn * 128; i += stride) {
        int b = i >> 7;
        int u = i & 127;
        int v = (u == 0) ? 0 : ((u <= Ln) ? ys[b * Ln + u - 1] : -1);
        gbias[i] = (v >= 0) ? bias[v] : 0.0f;
    }
}

// ---------------- unified GEMM ----------------
__global__ __launch_bounds__(256) void gemm_se(
    const unsigned short* __restrict__ hs_b, const unsigned short* __restrict__ w_b,
    const int* __restrict__ ys, const float* __restrict__ bias,
    const float* __restrict__ gbias, float* __restrict__ sep,
    float* __restrict__ glg2)
{
    __shared__ __align__(16) short lsA[128 * 64];
    __shared__ __align__(16) short lsB[128 * 64];

    const int tid = threadIdx.x;
    const int lane = tid & 63;
    const int w = tid >> 6;
    const int lr = lane & 15;
    const int kq = lane >> 4;
    const int m0 = blockIdx.x * 128;
    const int mw = w * 32;
    const bool gather = (blockIdx.y == NCB);
    const int b = blockIdx.x >> 2;

    const int srow = lane >> 3;
    const int scg  = (lane & 7) ^ (srow & 7);
    const int scol = scg * 8;

    const unsigned short* bptr[4];
    #pragma unroll
    for (int j = 0; j < 4; ++j) {
        int c = w * 4 + j;
        int row = c * 8 + srow;
        int v;
        if (gather) {
            if (row == 0) v = 0;
            else if (row <= Ln) v = ys[b * Ln + row - 1];
            else v = Vn + 32;                 // zero pad row of w_b
        } else {
            v = blockIdx.y * 128 + row;
        }
        bptr[j] = w_b + (size_t)v * Dn + scol;
    }

    f32x4 acc[2][8];
    #pragma unroll
    for (int mf = 0; mf < 2; ++mf)
        #pragma unroll
        for (int nf = 0; nf < 8; ++nf)
            acc[mf][nf] = (f32x4){0.f, 0.f, 0.f, 0.f};

    for (int ks = 0; ks < 4; ++ks) {
        const int k0 = ks * 64;
        __syncthreads();
        #pragma unroll
        for (int j = 0; j < 4; ++j) {
            int c = w * 4 + j;
            int row = c * 8 + srow;
            gl_lds16(hs_b + (size_t)(m0 + row) * Dn + k0 + scol, (char*)lsA + c * 1024);
            gl_lds16(bptr[j] + k0,                               (char*)lsB + c * 1024);
        }
        __syncthreads();

        #pragma unroll
        for (int sub = 0; sub < 2; ++sub) {
            short8 af[2], bf[8];
            #pragma unroll
            for (int mf = 0; mf < 2; ++mf) {
                int row = mw + mf * 16 + lr;
                int cg = (sub * 4 + kq) ^ (row & 7);
                af[mf] = *(const short8*)(&lsA[row * 64 + cg * 8]);
            }
            #pragma unroll
            for (int nf = 0; nf < 8; ++nf) {
                int row = nf * 16 + lr;
                int cg = (sub * 4 + kq) ^ (row & 7);
                bf[nf] = *(const short8*)(&lsB[row * 64 + cg * 8]);
            }
            #pragma unroll
            for (int mf = 0; mf < 2; ++mf)
                #pragma unroll
                for (int nf = 0; nf < 8; ++nf)
                    acc[mf][nf] = __builtin_amdgcn_mfma_f32_16x16x32_bf16(
                        af[mf], bf[nf], acc[mf][nf], 0, 0, 0);
        }
    }

    if (!gather) {
        const int n0 = blockIdx.y * 128;
        float bcol[8]; bool valid[8];
        #pragma unroll
        for (int nf = 0; nf < 8; ++nf) {
            int col = n0 + nf * 16 + lr;
            valid[nf] = (col < Vn);
            bcol[nf] = valid[nf] ? bias[col] : 0.0f;
        }
        #pragma unroll
        for (int mf = 0; mf < 2; ++mf) {
            #pragma unroll
            for (int r = 0; r < 4; ++r) {
                float s = 0.0f;
                #pragma unroll
                for (int nf = 0; nf < 8; ++nf)
                    if (valid[nf]) s += __expf(acc[mf][nf][r] + bcol[nf]);
                #pragma unroll
                for (int off = 1; off < 16; off <<= 1) s += __shfl_xor(s, off, 64);
                if (lr == 0)
                    sep[(size_t)blockIdx.y * Mtot + m0 + mw + mf * 16 + kq * 4 + r] = s;
            }
        }
    } else {
        #pragma unroll
        for (int mf = 0; mf < 2; ++mf) {
            #pragma unroll
            for (int nf = 0; nf < 5; ++nf) {
                int u = nf * 16 + lr;
                float gv = gbias[b * 128 + u];
                #pragma unroll
                for (int r = 0; r < 4; ++r) {
                    int g = m0 + mw + mf * 16 + kq * 4 + r;
                    glg2[(size_t)g * Un + u] = (acc[mf][nf][r] + gv) * INV_LN2;
                }
            }
        }
    }
}

// ---------------- lse + in-place normalize: glg2 <- exp2(glg2 - log2 sum) ----
__global__ __launch_bounds__(256) void lse_norm(
    const float* __restrict__ sep, float* __restrict__ glg2)
{
    __shared__ float sl[64];
    const int tid = threadIdx.x;
    const int g0 = blockIdx.x * 64;

    if (tid < 64) {
        float s = 0.0f;
        #pragma unroll
        for (int c = 0; c < NCB; ++c) s += sep[(size_t)c * Mtot + g0 + tid];
        sl[tid] = lg2(s);
    }
    __syncthreads();

    #pragma unroll
    for (int j = 0; j < 4; ++j) {
        int i = tid + j * 256;
        int row = i >> 4, u4 = (i & 15) * 4;
        float* p = glg2 + (size_t)(g0 + row) * Un + u4;
        float4 v = *(const float4*)p;
        float sub = sl[row];
        v.x = ex2(v.x - sub); v.y = ex2(v.y - sub);
        v.z = ex2(v.z - sub); v.w = ex2(v.w - sub);
        *(float4*)p = v;
    }
    if (tid < 64) {
        float* p = glg2 + (size_t)(g0 + tid) * Un + 64;
        *p = ex2(*p - sl[tid]);
    }
}

// ---------------- CTC forward recursion ----------------
// Linear f32 mantissa + per-lane int storage scale, renorm every 4 steps
// (r17's scale policy: nonzero lanes keep own exact scale, zero lanes adopt
// left neighbor's). NEW: q/r LDS reads prefetched TWO windows ahead through
// a 3-set named-register rotation (qa/qb/qc, ra/rb/rc) so ~120cy ds_read
// latency never sits on the dependent chain.
__global__ __launch_bounds__(256) void ctc_fwd(
    const float* __restrict__ pmat, const int* __restrict__ ys,
    const int* __restrict__ hlens, const int* __restrict__ ylens,
    float* __restrict__ out)
{
    __shared__ float ls[2][64 * CS + 4];
    __shared__ float shO[64], shE[64], shZ[64];
    __shared__ int   shX[64];

    const int b = blockIdx.x;
    const int tid = threadIdx.x;
    const int l = tid & 63;

    const int hl = hlens[b];
    int yl  = ys[b * Ln + l];
    int ylm = (l >= 1) ? ys[b * Ln + l - 1] : -1;
    const float aF = ((l >= 1) && (yl != ylm)) ? 1.0f : 0.0f;

    const float* pm = pmat + (size_t)b * Tn * Un;

    // stage chunk 0 (row tt <-> t = 1 + tt)
    #pragma unroll
    for (int j = 0; j < 4; ++j) {
        int i = tid + j * 256;
        int tt = i >> 4, u4 = (i & 15) * 4;
        *(float4*)(&ls[0][tt * CS + u4]) = *(const float4*)(pm + (size_t)(1 + tt) * Un + u4);
    }
    if (tid < 64) ls[0][tid * CS + 64] = pm[(size_t)(1 + tid) * Un + 64];
    __syncthreads();

    // t=0 init (all lanes scale 0)
    float o = (l == 0) ? pm[1] : 0.0f;
    float e = (l == 0) ? pm[0] : 0.0f;
    float z = 0.0f;
    int ex = 0;
    int dn = 0;

    float4 r4a = make_float4(0.f,0.f,0.f,0.f), r4b = r4a, r4c = r4a, r4d = r4a;
    float r1 = 0.0f;

    float qa0, qa1, qa2, qa3, ra0, ra1, ra2, ra3;
    float qb0, qb1, qb2, qb3, rb0, rb1, rb2, rb3;
    float qc0, qc1, qc2, qc3, rc0, rc1, rc2, rc3;

#define RENORM do { \
        float mm = fmaxf(fmaxf(o, e), z); \
        bool nz = (mm > 0.0f); \
        int dd = nz ? ((int)((__float_as_uint(mm) >> 23) & 255u) - 127) : 0; \
        o = ldexpf(o, -dd); e = ldexpf(e, -dd); z = ldexpf(z, -dd); \
        int exT = ex + dd; \
        int xm1 = dpp_shr1_i(exT, -(1 << 28)); \
        int et = nz ? exT : xm1; \
        ex = et; \
        int xet = dpp_shr1_i(et, -(1 << 28)); \
        dn = xet - ex; \
    } while (0)

#define STEPR(qv, rv) do { \
        float om1 = dpp_shr1_f(o, 0.0f); \
        float an  = ldexpf(om1, dn); \
        float nO = fmaf(aF, an, o + e) * (rv); \
        float nE = (e + an) * (qv); \
        float nZ = (z + o) * (qv); \
        o = nO; e = nE; z = nZ; \
    } while (0)

#define LDA(base) do { \
        qa0 = buf[(base) * CS];       ra0 = buf[(base) * CS + 1 + l]; \
        qa1 = buf[((base)+1) * CS];   ra1 = buf[((base)+1) * CS + 1 + l]; \
        qa2 = buf[((base)+2) * CS];   ra2 = buf[((base)+2) * CS + 1 + l]; \
        qa3 = buf[((base)+3) * CS];   ra3 = buf[((base)+3) * CS + 1 + l]; \
    } while (0)
#define LDB(base) do { \
        qb0 = buf[(base) * CS];       rb0 = buf[(base) * CS + 1 + l]; \
        qb1 = buf[((base)+1) * CS];   rb1 = buf[((base)+1) * CS + 1 + l]; \
        qb2 = buf[((base)+2) * CS];   rb2 = buf[((base)+2) * CS + 1 + l]; \
        qb3 = buf[((base)+3) * CS];   rb3 = buf[((base)+3) * CS + 1 + l]; \
    } while (0)
#define LDC(base) do { \
        qc0 = buf[(base) * CS];       rc0 = buf[(base) * CS + 1 + l]; \
        qc1 = buf[((base)+1) * CS];   rc1 = buf[((base)+1) * CS + 1 + l]; \
        qc2 = buf[((base)+2) * CS];   rc2 = buf[((base)+2) * CS + 1 + l]; \
        qc3 = buf[((base)+3) * CS];   rc3 = buf[((base)+3) * CS + 1 + l]; \
    } while (0)

#define W4A do { RENORM; STEPR(qa0,ra0); STEPR(qa1,ra1); STEPR(qa2,ra2); STEPR(qa3,ra3); } while (0)
#define W4B do { RENORM; STEPR(qb0,rb0); STEPR(qb1,rb1); STEPR(qb2,rb2); STEPR(qb3,rb3); } while (0)
#define W4C do { RENORM; STEPR(qc0,rc0); STEPR(qc1,rc1); STEPR(qc2,rc2); STEPR(qc3,rc3); } while (0)

// predicated fallback step (partial chunks; never taken when hl == Tn)
#define STEPS(Joff, ACT) do { \
        RENORM; \
        float q = buf[(Joff) * CS]; \
        float r = buf[(Joff) * CS + 1 + l]; \
        float om1 = dpp_shr1_f(o, 0.0f); \
        float an  = ldexpf(om1, dn); \
        float nO = fmaf(aF, an, o + e) * r; \
        float nE = (e + an) * q; \
        float nZ = (z + o) * q; \
        bool act = (ACT); \
        o = act ? nO : o; e = act ? nE : e; z = act ? nZ : z; \
    } while (0)

    for (int c = 0; c < 8; ++c) {
        if (c < 7) {
            const int tb = 1 + (c + 1) * 64;
            { int i = tid;       int tt = i >> 4, u4 = (i & 15) * 4;
              r4a = (tb + tt < Tn) ? *(const float4*)(pm + (size_t)(tb + tt) * Un + u4) : make_float4(0.f,0.f,0.f,0.f); }
            { int i = tid + 256; int tt = i >> 4, u4 = (i & 15) * 4;
              r4b = (tb + tt < Tn) ? *(const float4*)(pm + (size_t)(tb + tt) * Un + u4) : make_float4(0.f,0.f,0.f,0.f); }
            { int i = tid + 512; int tt = i >> 4, u4 = (i & 15) * 4;
              r4c = (tb + tt < Tn) ? *(const float4*)(pm + (size_t)(tb + tt) * Un + u4) : make_float4(0.f,0.f,0.f,0.f); }
            { int i = tid + 768; int tt = i >> 4, u4 = (i & 15) * 4;
              r4d = (tb + tt < Tn) ? *(const float4*)(pm + (size_t)(tb + tt) * Un + u4) : make_float4(0.f,0.f,0.f,0.f); }
            if (tid < 64)
                r1 = (tb + tid < Tn) ? pm[(size_t)(tb + tid) * Un + 64] : 0.0f;
        }

        const float* buf = ls[c & 1];

        if (c < 7) {
            if (hl >= (c + 1) * 64 + 1) {
                LDA(0); LDB(4);
                LDC(8);  W4A;     // w0  rows 0-3
                LDA(12); W4B;     // w1  rows 4-7
                LDB(16); W4C;     // w2  rows 8-11
                LDC(20); W4A;     // w3  rows 12-15
                LDA(24); W4B;     // w4  rows 16-19
                LDB(28); W4C;     // w5  rows 20-23
                LDC(32); W4A;     // w6  rows 24-27
                LDA(36); W4B;     // w7  rows 28-31
                LDB(40); W4C;     // w8  rows 32-35
                LDC(44); W4A;     // w9  rows 36-39
                LDA(48); W4B;     // w10 rows 40-43
                LDB(52); W4C;     // w11 rows 44-47
                LDC(56); W4A;     // w12 rows 48-51
                LDA(60); W4B;     // w13 rows 52-55
                W4C;              // w14 rows 56-59
                W4A;              // w15 rows 60-63
            } else {
                #pragma unroll 1
                for (int j = 0; j < 64; ++j)
                    STEPS(j, (c * 64 + 1 + j) < hl);
            }
        } else {
            if (hl >= Tn) {
                LDA(0); LDB(4);
                LDC(8);  W4A;
                LDA(12); W4B;
                LDB(16); W4C;
                LDC(20); W4A;
                LDA(24); W4B;
                LDB(28); W4C;
                LDC(32); W4A;
                LDA(36); W4B;
                LDB(40); W4C;
                LDC(44); W4A;
                LDA(48); W4B;
                LDB(52); W4C;
                LDC(56); W4A;
                LDA(60); W4B;
                W4C;                               // w14 rows 56-59
                RENORM;                            // partial w15: rows 60-62
                STEPR(qa0, ra0); STEPR(qa1, ra1); STEPR(qa2, ra2);
            } else {
                #pragma unroll 1
                for (int j = 0; j < 63; ++j)
                    STEPS(j, (449 + j) < hl);
            }
        }

        if (c < 7) {
            float* dst = ls[(c + 1) & 1];
            { int i = tid;       int tt = i >> 4, u4 = (i & 15) * 4; *(float4*)(&dst[tt * CS + u4]) = r4a; }
            { int i = tid + 256; int tt = i >> 4, u4 = (i & 15) * 4; *(float4*)(&dst[tt * CS + u4]) = r4b; }
            { int i = tid + 512; int tt = i >> 4, u4 = (i & 15) * 4; *(float4*)(&dst[tt * CS + u4]) = r4c; }
            { int i = tid + 768; int tt = i >> 4, u4 = (i & 15) * 4; *(float4*)(&dst[tt * CS + u4]) = r4d; }
            if (tid < 64) dst[tid * CS + 64] = r1;
        }
        __syncthreads();
    }
#undef RENORM
#undef STEPR
#undef LDA
#undef LDB
#undef LDC
#undef W4A
#undef W4B
#undef W4C
#undef STEPS

    if (tid < 64) { shO[l] = o; shE[l] = e; shZ[l] = z; shX[l] = ex; }
    __syncthreads();

    if (tid == 0) {
        int L = ylens[b];
        float vo = shO[L - 1]; int xo = shX[L - 1];     // alpha[2L-1]
        float ve; int xe;                                // alpha[2L]
        if (L == 64) { ve = shZ[63]; xe = shX[63]; }
        else         { ve = shE[L];  xe = shX[L]; }
        int em = (xo > xe) ? xo : xe;
        float s = ldexpf(vo, xo - em) + ldexpf(ve, xe - em);
        float ll = (lg2(s) + (float)em) * LN2;
        atomicAdd(out, -ll / (float)Bn);
    }
}

extern "C" void kernel_launch(void* const* d_in, const int* in_sizes, int n_in,
                              void* d_out, int out_size, void* d_ws, size_t ws_size,
                              hipStream_t stream) {
    const float* hs    = (const float*)d_in[0];
    const int*   hlens = (const int*)d_in[1];
    const int*   ys    = (const int*)d_in[2];
    const int*   ylens = (const int*)d_in[3];
    const float* W     = (const float*)d_in[4];
    const float* bias  = (const float*)d_in[5];
    float* out = (float*)d_out;

    char* ws = (char*)d_ws;
    unsigned short* hs_b = (unsigned short*)(ws);                       // 4,194,304 B
    unsigned short* w_b  = (unsigned short*)(ws + 4194304);             // 2,228,224 B
    float* glg2  = (float*)(ws + 6422528);                              // 2,621,440 B
    float* sep   = (float*)(ws + 9043968);                              // 1,114,112 B
    float* gbias = (float*)(ws + 10158080);                             //     8,192 B

    conv<<<1024, 256, 0, stream>>>(hs, W, bias, ys, hs_b, w_b, gbias, out);
    gemm_se<<<dim3(64, NCB + 1), 256, 0, stream>>>(hs_b, w_b, ys, bias, gbias, sep, glg2);
    lse_norm<<<Mtot / 64, 256, 0, stream>>>(sep, glg2);   // glg2 -> linear probs in place
    ctc_fwd<<<Bn, 256, 0, stream>>>(glg2, ys, hlens, ylens, out);
}